// Round 1
// baseline (1172.835 us; speedup 1.0000x reference)
//
#include <hip/hip_runtime.h>
#include <hip/hip_fp16.h>

typedef unsigned short u16;
typedef unsigned int u32;

#define N_NODE 50000
#define N_EDGE 250000
#define NNZV   500000

typedef __attribute__((ext_vector_type(8))) __bf16 bf16x8;
typedef __attribute__((ext_vector_type(4))) float f32x4;

static __device__ __forceinline__ u16 f2bf(float f) {
  union { float f; u32 u; } cv; cv.f = f;
  u32 u = cv.u;
  return (u16)((u + 0x7FFFu + ((u >> 16) & 1u)) >> 16);
}

static __device__ __forceinline__ float gelu_f(float x) {
  return 0.5f * x * (1.0f + erff(x * 0.70710678118654752f));
}

// out[n*K+k] = bf16(in[k*N+n])  (weights stored [in=K][out=N] -> bf16 [N][K])
__global__ void transpose_cvt_kernel(const float* __restrict__ in, u16* __restrict__ out,
                                     int K, int N) {
  int idx = blockIdx.x * 256 + threadIdx.x;
  if (idx < K * N) {
    int k = idx % K, n = idx / K;
    out[idx] = f2bf(in[(size_t)k * N + n]);
  }
}

// ---------------- edge MLP: 64 edges/block, 4 waves, wave owns 16 rows ----------
__global__ __launch_bounds__(256) void edge_mlp_kernel(
    const float* __restrict__ node, const float* __restrict__ edge,
    const int* __restrict__ edgeIdx,
    const float* __restrict__ lng, const float* __restrict__ lnb,
    const u16* __restrict__ w1t, const float* __restrict__ fb1,
    const u16* __restrict__ w2t, const float* __restrict__ fb2,
    __half* __restrict__ e_h, float* __restrict__ out_edge, int write_eh) {
  const int lane = threadIdx.x & 63;
  const int wid = threadIdx.x >> 6;
  const int row0 = blockIdx.x * 64;

  __shared__ __align__(16) u16 xt[64][392];   // 384 + 8 pad
  __shared__ __align__(16) u16 ht[64][136];   // 128 + 8 pad

  float ga[6], be[6];
#pragma unroll
  for (int s = 0; s < 3; ++s) {
    float2 g2 = *(const float2*)&lng[s * 128 + 2 * lane];
    float2 b2 = *(const float2*)&lnb[s * 128 + 2 * lane];
    ga[2 * s] = g2.x; ga[2 * s + 1] = g2.y;
    be[2 * s] = b2.x; be[2 * s + 1] = b2.y;
  }

  // stage + layernorm: one wave per edge row (16 rows per wave)
  for (int r = 0; r < 16; ++r) {
    int lr = wid * 16 + r;
    int gi = row0 + lr; if (gi >= N_EDGE) gi = N_EDGE - 1;
    int ia = edgeIdx[2 * gi], ib = edgeIdx[2 * gi + 1];
    float2 v0 = *(const float2*)&edge[(size_t)gi * 128 + 2 * lane];
    float2 v1 = *(const float2*)&node[(size_t)ia * 128 + 2 * lane];
    float2 v2 = *(const float2*)&node[(size_t)ib * 128 + 2 * lane];
    float s  = v0.x + v0.y + v1.x + v1.y + v2.x + v2.y;
    float ss = v0.x*v0.x + v0.y*v0.y + v1.x*v1.x + v1.y*v1.y + v2.x*v2.x + v2.y*v2.y;
#pragma unroll
    for (int m = 1; m < 64; m <<= 1) {
      s  += __shfl_xor(s, m);
      ss += __shfl_xor(ss, m);
    }
    float mean = s * (1.0f / 384.0f);
    float var  = ss * (1.0f / 384.0f) - mean * mean;
    float rstd = rsqrtf(var + 1e-5f);
    float2 vv[3] = {v0, v1, v2};
#pragma unroll
    for (int sg = 0; sg < 3; ++sg) {
      float y0 = (vv[sg].x - mean) * rstd * ga[2 * sg]     + be[2 * sg];
      float y1 = (vv[sg].y - mean) * rstd * ga[2 * sg + 1] + be[2 * sg + 1];
      u32 p = (u32)f2bf(y0) | ((u32)f2bf(y1) << 16);
      *(u32*)&xt[lr][sg * 128 + 2 * lane] = p;
    }
  }
  __syncthreads();

  const int l15  = lane & 15;
  const int koff = (lane >> 4) * 8;
  const int arow = wid * 16 + l15;

  f32x4 acc2[8];
#pragma unroll
  for (int nt = 0; nt < 8; ++nt) {
    float bv = fb2[nt * 16 + l15];
    acc2[nt] = (f32x4){bv, bv, bv, bv};
  }

  for (int c = 0; c < 3; ++c) {
    f32x4 acc1[8];
#pragma unroll
    for (int nt = 0; nt < 8; ++nt) {
      float bv = fb1[c * 128 + nt * 16 + l15];
      acc1[nt] = (f32x4){bv, bv, bv, bv};
    }
#pragma unroll
    for (int kk = 0; kk < 12; ++kk) {
      bf16x8 a = *(const bf16x8*)&xt[arow][kk * 32 + koff];
#pragma unroll
      for (int nt = 0; nt < 8; ++nt) {
        bf16x8 b = *(const bf16x8*)&w1t[(size_t)(c * 128 + nt * 16 + l15) * 384 + kk * 32 + koff];
        acc1[nt] = __builtin_amdgcn_mfma_f32_16x16x32_bf16(a, b, acc1[nt], 0, 0, 0);
      }
    }
#pragma unroll
    for (int nt = 0; nt < 8; ++nt) {
#pragma unroll
      for (int j = 0; j < 4; ++j) {
        float g = gelu_f(acc1[nt][j]);
        ht[wid * 16 + (lane >> 4) * 4 + j][nt * 16 + l15] = f2bf(g);
      }
    }
    __syncthreads();
#pragma unroll
    for (int kk = 0; kk < 4; ++kk) {
      bf16x8 a2 = *(const bf16x8*)&ht[arow][kk * 32 + koff];
#pragma unroll
      for (int nt = 0; nt < 8; ++nt) {
        bf16x8 b = *(const bf16x8*)&w2t[(size_t)(nt * 16 + l15) * 384 + c * 128 + kk * 32 + koff];
        acc2[nt] = __builtin_amdgcn_mfma_f32_16x16x32_bf16(a2, b, acc2[nt], 0, 0, 0);
      }
    }
    __syncthreads();
  }

#pragma unroll
  for (int nt = 0; nt < 8; ++nt) {
#pragma unroll
    for (int j = 0; j < 4; ++j) {
      int lr = wid * 16 + (lane >> 4) * 4 + j;
      int gi = row0 + lr;
      if (gi < N_EDGE) {
        int col = nt * 16 + l15;
        __half hv = __float2half(acc2[nt][j]);
        if (write_eh) e_h[(size_t)gi * 128 + col] = hv;
        out_edge[(size_t)gi * 128 + col] = edge[(size_t)gi * 128 + col] + __half2float(hv);
      }
    }
  }
}

// ---------------- scatter: agg[row] += fp16(e_h[col] * val), pk fp16 atomics ----
__global__ __launch_bounds__(256) void scatter_kernel(
    const int* __restrict__ rows, const int* __restrict__ cols,
    const float* __restrict__ vals,
    const __half* __restrict__ e_h,
    const float* __restrict__ out_edge, const float* __restrict__ edge,
    __half* __restrict__ agg, int use_eh) {
  long t = (long)blockIdx.x * 256 + threadIdx.x;
  int k = (int)(t >> 6);
  int l = (int)(t & 63);
  int r = rows[k], c = cols[k];
  float v = vals[k];
  __half2 h2;
  if (use_eh) {
    h2 = *(const __half2*)&e_h[(size_t)c * 128 + 2 * l];
  } else {
    size_t o = (size_t)c * 128 + 2 * l;
    float2 eo = *(const float2*)&out_edge[o];
    float2 e0 = *(const float2*)&edge[o];
    h2 = __floats2half2_rn(eo.x - e0.x, eo.y - e0.y);
  }
  __half2 vv = __float2half2_rn(v);
  h2 = __hmul2(h2, vv);
  unsafeAtomicAdd((__half2*)&agg[(size_t)r * 128 + 2 * l], h2);
}

// ---------------- node MLP: 64 nodes/block --------------------------------------
__global__ __launch_bounds__(256) void node_mlp_kernel(
    const float* __restrict__ node, const __half* __restrict__ agg,
    const float* __restrict__ lng, const float* __restrict__ lnb,
    const u16* __restrict__ w1t, const float* __restrict__ fb1,
    const u16* __restrict__ w2t, const float* __restrict__ fb2,
    float* __restrict__ out_node) {
  const int lane = threadIdx.x & 63;
  const int wid = threadIdx.x >> 6;
  const int row0 = blockIdx.x * 64;

  __shared__ __align__(16) u16 xt[64][264];   // 256 + 8 pad
  __shared__ __align__(16) u16 ht[64][136];

  float ga[4], be[4];
#pragma unroll
  for (int s = 0; s < 2; ++s) {
    float2 g2 = *(const float2*)&lng[s * 128 + 2 * lane];
    float2 b2 = *(const float2*)&lnb[s * 128 + 2 * lane];
    ga[2 * s] = g2.x; ga[2 * s + 1] = g2.y;
    be[2 * s] = b2.x; be[2 * s + 1] = b2.y;
  }

  for (int r = 0; r < 16; ++r) {
    int lr = wid * 16 + r;
    int gi = row0 + lr; if (gi >= N_NODE) gi = N_NODE - 1;
    float2 v0 = *(const float2*)&node[(size_t)gi * 128 + 2 * lane];
    __half2 h2 = *(const __half2*)&agg[(size_t)gi * 128 + 2 * lane];
    float2 v1 = __half22float2(h2);
    float s  = v0.x + v0.y + v1.x + v1.y;
    float ss = v0.x*v0.x + v0.y*v0.y + v1.x*v1.x + v1.y*v1.y;
#pragma unroll
    for (int m = 1; m < 64; m <<= 1) {
      s  += __shfl_xor(s, m);
      ss += __shfl_xor(ss, m);
    }
    float mean = s * (1.0f / 256.0f);
    float var  = ss * (1.0f / 256.0f) - mean * mean;
    float rstd = rsqrtf(var + 1e-5f);
    float2 vv[2] = {v0, v1};
#pragma unroll
    for (int sg = 0; sg < 2; ++sg) {
      float y0 = (vv[sg].x - mean) * rstd * ga[2 * sg]     + be[2 * sg];
      float y1 = (vv[sg].y - mean) * rstd * ga[2 * sg + 1] + be[2 * sg + 1];
      u32 p = (u32)f2bf(y0) | ((u32)f2bf(y1) << 16);
      *(u32*)&xt[lr][sg * 128 + 2 * lane] = p;
    }
  }
  __syncthreads();

  const int l15  = lane & 15;
  const int koff = (lane >> 4) * 8;
  const int arow = wid * 16 + l15;

  f32x4 acc2[8];
#pragma unroll
  for (int nt = 0; nt < 8; ++nt) {
    float bv = fb2[nt * 16 + l15];
    acc2[nt] = (f32x4){bv, bv, bv, bv};
  }

  for (int c = 0; c < 2; ++c) {
    f32x4 acc1[8];
#pragma unroll
    for (int nt = 0; nt < 8; ++nt) {
      float bv = fb1[c * 128 + nt * 16 + l15];
      acc1[nt] = (f32x4){bv, bv, bv, bv};
    }
#pragma unroll
    for (int kk = 0; kk < 8; ++kk) {
      bf16x8 a = *(const bf16x8*)&xt[arow][kk * 32 + koff];
#pragma unroll
      for (int nt = 0; nt < 8; ++nt) {
        bf16x8 b = *(const bf16x8*)&w1t[(size_t)(c * 128 + nt * 16 + l15) * 256 + kk * 32 + koff];
        acc1[nt] = __builtin_amdgcn_mfma_f32_16x16x32_bf16(a, b, acc1[nt], 0, 0, 0);
      }
    }
#pragma unroll
    for (int nt = 0; nt < 8; ++nt) {
#pragma unroll
      for (int j = 0; j < 4; ++j) {
        float g = gelu_f(acc1[nt][j]);
        ht[wid * 16 + (lane >> 4) * 4 + j][nt * 16 + l15] = f2bf(g);
      }
    }
    __syncthreads();
#pragma unroll
    for (int kk = 0; kk < 4; ++kk) {
      bf16x8 a2 = *(const bf16x8*)&ht[arow][kk * 32 + koff];
#pragma unroll
      for (int nt = 0; nt < 8; ++nt) {
        bf16x8 b = *(const bf16x8*)&w2t[(size_t)(nt * 16 + l15) * 256 + c * 128 + kk * 32 + koff];
        acc2[nt] = __builtin_amdgcn_mfma_f32_16x16x32_bf16(a2, b, acc2[nt], 0, 0, 0);
      }
    }
    __syncthreads();
  }

#pragma unroll
  for (int nt = 0; nt < 8; ++nt) {
#pragma unroll
    for (int j = 0; j < 4; ++j) {
      int lr = wid * 16 + (lane >> 4) * 4 + j;
      int gi = row0 + lr;
      if (gi < N_NODE) {
        int col = nt * 16 + l15;
        out_node[(size_t)gi * 128 + col] = node[(size_t)gi * 128 + col] + acc2[nt][j];
      }
    }
  }
}

extern "C" void kernel_launch(void* const* d_in, const int* in_sizes, int n_in,
                              void* d_out, int out_size, void* d_ws, size_t ws_size,
                              hipStream_t stream) {
  const float* node    = (const float*)d_in[0];
  const float* edge    = (const float*)d_in[1];
  const int*   edgeIdx = (const int*)d_in[2];
  const int*   rows    = (const int*)d_in[3];
  const int*   cols    = (const int*)d_in[4];
  const float* vals    = (const float*)d_in[5];
  const float* n1g     = (const float*)d_in[6];
  const float* n1b     = (const float*)d_in[7];
  const float* n2g     = (const float*)d_in[8];
  const float* n2b     = (const float*)d_in[9];
  const float* ew1     = (const float*)d_in[10];
  const float* eb1     = (const float*)d_in[11];
  const float* ew2     = (const float*)d_in[12];
  const float* eb2     = (const float*)d_in[13];
  const float* nw1     = (const float*)d_in[14];
  const float* nb1     = (const float*)d_in[15];
  const float* nw2     = (const float*)d_in[16];
  const float* nb2     = (const float*)d_in[17];

  float* out_node = (float*)d_out;
  float* out_edge = out_node + (size_t)N_NODE * 128;

  char* w = (char*)d_ws;
  u16* ew1t = (u16*)w; w += (size_t)384 * 384 * 2;
  u16* ew2t = (u16*)w; w += (size_t)128 * 384 * 2;
  u16* nw1t = (u16*)w; w += (size_t)256 * 256 * 2;
  u16* nw2t = (u16*)w; w += (size_t)128 * 256 * 2;
  __half* agg = (__half*)w; w += (size_t)N_NODE * 128 * 2;
  __half* e_h = (__half*)w; w += (size_t)N_EDGE * 128 * 2;
  size_t need_full = (size_t)(w - (char*)d_ws);
  int use_eh = (ws_size >= need_full) ? 1 : 0;

  transpose_cvt_kernel<<<(384 * 384 + 255) / 256, 256, 0, stream>>>(ew1, ew1t, 384, 384);
  transpose_cvt_kernel<<<(384 * 128 + 255) / 256, 256, 0, stream>>>(ew2, ew2t, 384, 128);
  transpose_cvt_kernel<<<(256 * 256 + 255) / 256, 256, 0, stream>>>(nw1, nw1t, 256, 256);
  transpose_cvt_kernel<<<(256 * 128 + 255) / 256, 256, 0, stream>>>(nw2, nw2t, 256, 128);
  hipMemsetAsync(agg, 0, (size_t)N_NODE * 128 * 2, stream);

  edge_mlp_kernel<<<(N_EDGE + 63) / 64, 256, 0, stream>>>(
      node, edge, edgeIdx, n1g, n1b, ew1t, eb1, ew2t, eb2, e_h, out_edge, use_eh);
  scatter_kernel<<<(NNZV * 64) / 256, 256, 0, stream>>>(
      rows, cols, vals, e_h, out_edge, edge, agg, use_eh);
  node_mlp_kernel<<<(N_NODE + 63) / 64, 256, 0, stream>>>(
      node, agg, n2g, n2b, nw1t, nb1, nw2t, nb2, out_node);
}

// Round 2
// 748.044 us; speedup vs baseline: 1.5679x; 1.5679x over previous
//
#include <hip/hip_runtime.h>
#include <hip/hip_fp16.h>

typedef unsigned short u16;
typedef unsigned int u32;

#define N_NODE 50000
#define N_EDGE 250000
#define NNZV   500000

typedef __attribute__((ext_vector_type(8))) __bf16 bf16x8;
typedef __attribute__((ext_vector_type(4))) float f32x4;

static __device__ __forceinline__ u16 f2bf(float f) {
  union { float f; u32 u; } cv; cv.f = f;
  u32 u = cv.u;
  return (u16)((u + 0x7FFFu + ((u >> 16) & 1u)) >> 16);
}

static __device__ __forceinline__ float gelu_f(float x) {
  return 0.5f * x * (1.0f + erff(x * 0.70710678118654752f));
}

// async global->LDS, 16B per lane; LDS dst = wave-uniform base + lane*16
static __device__ __forceinline__ void gload16(const u16* g, u16* l) {
  __builtin_amdgcn_global_load_lds(
      (const __attribute__((address_space(1))) void*)g,
      (__attribute__((address_space(3))) void*)l,
      16, 0, 0);
}

// out[n*K+k] = bf16(in[k*N+n])  (weights [in=K][out=N] -> bf16 [N][K])
__global__ void transpose_cvt_kernel(const float* __restrict__ in, u16* __restrict__ out,
                                     int K, int N) {
  int idx = blockIdx.x * 256 + threadIdx.x;
  if (idx < K * N) {
    int k = idx % K, n = idx / K;
    out[idx] = f2bf(in[(size_t)k * N + n]);
  }
}

// ---------------- LN kernels: one wave per row -------------------------------
__global__ __launch_bounds__(256) void ln_edge_kernel(
    const float* __restrict__ edge_c, const float* __restrict__ node,
    const int* __restrict__ eidx_c,
    const float* __restrict__ g, const float* __restrict__ b,
    u16* __restrict__ x, int rows) {
  int lane = threadIdx.x & 63, wid = threadIdx.x >> 6;
  int lr = blockIdx.x * 4 + wid;
  if (lr >= rows) return;
  int ia = eidx_c[2 * lr], ib = eidx_c[2 * lr + 1];
  float2 v0 = *(const float2*)&edge_c[(size_t)lr * 128 + 2 * lane];
  float2 v1 = *(const float2*)&node[(size_t)ia * 128 + 2 * lane];
  float2 v2 = *(const float2*)&node[(size_t)ib * 128 + 2 * lane];
  float s  = v0.x + v0.y + v1.x + v1.y + v2.x + v2.y;
  float ss = v0.x*v0.x + v0.y*v0.y + v1.x*v1.x + v1.y*v1.y + v2.x*v2.x + v2.y*v2.y;
#pragma unroll
  for (int m = 1; m < 64; m <<= 1) { s += __shfl_xor(s, m); ss += __shfl_xor(ss, m); }
  float mean = s * (1.0f / 384.0f);
  float var  = ss * (1.0f / 384.0f) - mean * mean;
  float rstd = rsqrtf(var + 1e-5f);
  float2 vv[3] = {v0, v1, v2};
#pragma unroll
  for (int sg = 0; sg < 3; ++sg) {
    float2 g2 = *(const float2*)&g[sg * 128 + 2 * lane];
    float2 b2 = *(const float2*)&b[sg * 128 + 2 * lane];
    float y0 = (vv[sg].x - mean) * rstd * g2.x + b2.x;
    float y1 = (vv[sg].y - mean) * rstd * g2.y + b2.y;
    *(u32*)&x[(size_t)lr * 384 + sg * 128 + 2 * lane] = (u32)f2bf(y0) | ((u32)f2bf(y1) << 16);
  }
}

__global__ __launch_bounds__(256) void ln_node_kernel(
    const float* __restrict__ node_c, const __half* __restrict__ agg_c,
    const float* __restrict__ g, const float* __restrict__ b,
    u16* __restrict__ x, int rows) {
  int lane = threadIdx.x & 63, wid = threadIdx.x >> 6;
  int lr = blockIdx.x * 4 + wid;
  if (lr >= rows) return;
  float2 v0 = *(const float2*)&node_c[(size_t)lr * 128 + 2 * lane];
  float2 v1 = __half22float2(*(const __half2*)&agg_c[(size_t)lr * 128 + 2 * lane]);
  float s  = v0.x + v0.y + v1.x + v1.y;
  float ss = v0.x*v0.x + v0.y*v0.y + v1.x*v1.x + v1.y*v1.y;
#pragma unroll
  for (int m = 1; m < 64; m <<= 1) { s += __shfl_xor(s, m); ss += __shfl_xor(ss, m); }
  float mean = s * (1.0f / 256.0f);
  float var  = ss * (1.0f / 256.0f) - mean * mean;
  float rstd = rsqrtf(var + 1e-5f);
  float2 vv[2] = {v0, v1};
#pragma unroll
  for (int sg = 0; sg < 2; ++sg) {
    float2 g2 = *(const float2*)&g[sg * 128 + 2 * lane];
    float2 b2 = *(const float2*)&b[sg * 128 + 2 * lane];
    float y0 = (vv[sg].x - mean) * rstd * g2.x + b2.x;
    float y1 = (vv[sg].y - mean) * rstd * g2.y + b2.y;
    *(u32*)&x[(size_t)lr * 256 + sg * 128 + 2 * lane] = (u32)f2bf(y0) | ((u32)f2bf(y1) << 16);
  }
}

// ---------------- GEMM: 128x128 tile, 4 waves (wave 64x64), dbuf LDS ----------
// A [Mrows][K] bf16, B [N_ALL][K] bf16 (pre-transposed). K % 32 == 0.
// EPI 0: h_out = bf16(gelu(y)), stride N_ALL
// EPI 1: hv=fp16(y); out_f = res_in + float(hv); optional e_h = hv   (N_ALL=128)
// EPI 2: out_f = res_in + y                                          (N_ALL=128)
template<int EPI>
__global__ __launch_bounds__(256, 4) void gemm_kernel(
    const u16* __restrict__ A, const u16* __restrict__ B,
    const float* __restrict__ bias,
    int Mrows, int K, int N_ALL,
    u16* __restrict__ h_out,
    const float* __restrict__ res_in, float* __restrict__ out_f,
    __half* __restrict__ e_h, int store_eh) {
  const int lane = threadIdx.x & 63;
  const int wid  = threadIdx.x >> 6;      // 0..3
  const int wm   = wid >> 1, wn = wid & 1;
  const int l15  = lane & 15, gq = lane >> 4;
  const int brow = blockIdx.x * 128;
  const int n0   = blockIdx.y * 128;

  __shared__ __align__(16) u16 As[2][128 * 32];
  __shared__ __align__(16) u16 Bs[2][128 * 32];

  const int NS = K >> 5;

  // ---- staging lane mapping (2 A-rows + 2 B-rows of 16 per wave per slab) ----
  // XOR chunk swizzle: phys chunk p holds logical chunk g = p ^ ((row>>1)&3)
  const int sr0 = wid * 32 + (lane >> 2);
  const int sr1 = sr0 + 16;
  const int sp  = lane & 3;
  const int sg0 = sp ^ ((sr0 >> 1) & 3);
  const int sg1 = sp ^ ((sr1 >> 1) & 3);
  int ar0 = brow + sr0; if (ar0 >= Mrows) ar0 = Mrows - 1;
  int ar1 = brow + sr1; if (ar1 >= Mrows) ar1 = Mrows - 1;
  const u16* srcA0 = A + (size_t)ar0 * K + sg0 * 8;
  const u16* srcA1 = A + (size_t)ar1 * K + sg1 * 8;
  const u16* srcB0 = B + (size_t)(n0 + sr0) * K + sg0 * 8;
  const u16* srcB1 = B + (size_t)(n0 + sr1) * K + sg1 * 8;
  const int dst0 = (wid * 32) * 32;        // u16 offset, wave-uniform
  const int dst1 = (wid * 32 + 16) * 32;

  // ---- fragment read offsets: same swizzle, constant per lane ----
  const int pl   = gq ^ ((l15 >> 1) & 3);
  const int foff = l15 * 32 + pl * 8;      // within 16-row group

  f32x4 acc[4][4];
#pragma unroll
  for (int n = 0; n < 4; ++n) {
    float bv = bias[n0 + wn * 64 + n * 16 + l15];
#pragma unroll
    for (int m = 0; m < 4; ++m) acc[m][n] = (f32x4){bv, bv, bv, bv};
  }

  // prologue stage slab 0 -> buf 0
  gload16(srcA0, &As[0][dst0]);
  gload16(srcA1, &As[0][dst1]);
  gload16(srcB0, &Bs[0][dst0]);
  gload16(srcB1, &Bs[0][dst1]);
  __syncthreads();

  for (int ks = 0; ks < NS; ++ks) {
    const int buf = ks & 1;
    if (ks + 1 < NS) {
      const int koff = (ks + 1) * 32;
      gload16(srcA0 + koff, &As[buf ^ 1][dst0]);
      gload16(srcA1 + koff, &As[buf ^ 1][dst1]);
      gload16(srcB0 + koff, &Bs[buf ^ 1][dst0]);
      gload16(srcB1 + koff, &Bs[buf ^ 1][dst1]);
    }
    bf16x8 a[4], bb[4];
#pragma unroll
    for (int m = 0; m < 4; ++m)
      a[m] = *(const bf16x8*)&As[buf][(wm * 64 + m * 16) * 32 + foff];
#pragma unroll
    for (int n = 0; n < 4; ++n)
      bb[n] = *(const bf16x8*)&Bs[buf][(wn * 64 + n * 16) * 32 + foff];
#pragma unroll
    for (int m = 0; m < 4; ++m)
#pragma unroll
      for (int n = 0; n < 4; ++n)
        acc[m][n] = __builtin_amdgcn_mfma_f32_16x16x32_bf16(a[m], bb[n], acc[m][n], 0, 0, 0);
    __syncthreads();   // drains staging vmcnt + guards buffer reuse
  }

  // ---- epilogue: C frag row = gq*4+j, col = l15 ----
#pragma unroll
  for (int n = 0; n < 4; ++n) {
    const int col = n0 + wn * 64 + n * 16 + l15;
#pragma unroll
    for (int m = 0; m < 4; ++m) {
#pragma unroll
      for (int j = 0; j < 4; ++j) {
        int r = brow + wm * 64 + m * 16 + gq * 4 + j;
        if (r < Mrows) {
          float y = acc[m][n][j];
          if (EPI == 0) {
            h_out[(size_t)r * N_ALL + col] = f2bf(gelu_f(y));
          } else if (EPI == 1) {
            __half hv = __float2half(y);
            if (store_eh) e_h[(size_t)r * 128 + col] = hv;
            out_f[(size_t)r * 128 + col] = res_in[(size_t)r * 128 + col] + __half2float(hv);
          } else {
            out_f[(size_t)r * 128 + col] = res_in[(size_t)r * 128 + col] + y;
          }
        }
      }
    }
  }
}

// ---------------- scatter: agg[row] += fp16(e[col] * val), pk fp16 atomics ----
__global__ __launch_bounds__(256) void scatter_kernel(
    const int* __restrict__ rows, const int* __restrict__ cols,
    const float* __restrict__ vals,
    const __half* __restrict__ e_h,
    const float* __restrict__ out_edge, const float* __restrict__ edge,
    __half* __restrict__ agg, int use_eh) {
  long t = (long)blockIdx.x * 256 + threadIdx.x;
  int k = (int)(t >> 6);
  int l = (int)(t & 63);
  int r = rows[k], c = cols[k];
  float v = vals[k];
  __half2 h2;
  if (use_eh) {
    h2 = *(const __half2*)&e_h[(size_t)c * 128 + 2 * l];
  } else {
    size_t o = (size_t)c * 128 + 2 * l;
    float2 eo = *(const float2*)&out_edge[o];
    float2 e0 = *(const float2*)&edge[o];
    h2 = __floats2half2_rn(eo.x - e0.x, eo.y - e0.y);
  }
  h2 = __hmul2(h2, __float2half2_rn(v));
  unsafeAtomicAdd((__half2*)&agg[(size_t)r * 128 + 2 * l], h2);
}

extern "C" void kernel_launch(void* const* d_in, const int* in_sizes, int n_in,
                              void* d_out, int out_size, void* d_ws, size_t ws_size,
                              hipStream_t stream) {
  (void)in_sizes; (void)n_in; (void)out_size;
  const float* node    = (const float*)d_in[0];
  const float* edge    = (const float*)d_in[1];
  const int*   edgeIdx = (const int*)d_in[2];
  const int*   e2n_r   = (const int*)d_in[3];
  const int*   e2n_c   = (const int*)d_in[4];
  const float* e2n_v   = (const float*)d_in[5];
  const float* n1g     = (const float*)d_in[6];
  const float* n1b     = (const float*)d_in[7];
  const float* n2g     = (const float*)d_in[8];
  const float* n2b     = (const float*)d_in[9];
  const float* ew1     = (const float*)d_in[10];
  const float* eb1     = (const float*)d_in[11];
  const float* ew2     = (const float*)d_in[12];
  const float* eb2     = (const float*)d_in[13];
  const float* nw1     = (const float*)d_in[14];
  const float* nb1     = (const float*)d_in[15];
  const float* nw2     = (const float*)d_in[16];
  const float* nb2     = (const float*)d_in[17];

  float* out_node = (float*)d_out;
  float* out_edge = out_node + (size_t)N_NODE * 128;

  // ---- workspace carve (tiered on ws_size; proven floor is ~13.4MB) ----
  char* w = (char*)d_ws;
  auto alloc = [&](size_t bytes) { char* p = w; w += (bytes + 255) & ~(size_t)255; return p; };
  u16* ew1t = (u16*)alloc((size_t)384 * 384 * 2);
  u16* ew2t = (u16*)alloc((size_t)128 * 384 * 2);
  u16* nw1t = (u16*)alloc((size_t)256 * 256 * 2);
  u16* nw2t = (u16*)alloc((size_t)128 * 256 * 2);
  __half* agg = (__half*)alloc((size_t)N_NODE * 128 * 2);

  size_t used = (size_t)(w - (char*)d_ws);
  size_t avail = ws_size > used ? ws_size - used : 0;
  const size_t EH_BYTES = (size_t)N_EDGE * 128 * 2;   // 64MB
  int use_eh = (avail >= EH_BYTES + (size_t)(48 << 20)) ? 1 : 0;
  __half* e_h = nullptr;
  if (use_eh) e_h = (__half*)alloc(EH_BYTES);
  size_t area = ws_size > (size_t)(w - (char*)d_ws) ? ws_size - (size_t)(w - (char*)d_ws) : 0;

  long cha = (long)(area / 1536); cha &= ~255L;
  if (cha > 250112) cha = 250112;
  if (cha < 256) cha = 256;
  long chn = (long)(area / 1024); chn &= ~255L;
  if (chn > 50176) chn = 50176;
  if (chn < 256) chn = 256;

  u16* x_c  = (u16*)w;
  u16* h_c  = x_c + (size_t)cha * 384;
  u16* xn_c = (u16*)w;                      // node phase overlays edge chunk area
  u16* hn_c = xn_c + (size_t)chn * 256;

  // ---- prep ----
  transpose_cvt_kernel<<<(384 * 384 + 255) / 256, 256, 0, stream>>>(ew1, ew1t, 384, 384);
  transpose_cvt_kernel<<<(384 * 128 + 255) / 256, 256, 0, stream>>>(ew2, ew2t, 384, 128);
  transpose_cvt_kernel<<<(256 * 256 + 255) / 256, 256, 0, stream>>>(nw1, nw1t, 256, 256);
  transpose_cvt_kernel<<<(256 * 128 + 255) / 256, 256, 0, stream>>>(nw2, nw2t, 256, 128);
  hipMemsetAsync(agg, 0, (size_t)N_NODE * 128 * 2, stream);

  // ---- edge path (chunked) ----
  for (long r0 = 0; r0 < N_EDGE; r0 += cha) {
    int rows = (int)((N_EDGE - r0) < cha ? (N_EDGE - r0) : cha);
    ln_edge_kernel<<<(rows + 3) / 4, 256, 0, stream>>>(
        edge + (size_t)r0 * 128, node, edgeIdx + (size_t)r0 * 2, n1g, n1b, x_c, rows);
    dim3 g1((rows + 127) / 128, 3);
    gemm_kernel<0><<<g1, 256, 0, stream>>>(x_c, ew1t, eb1, rows, 384, 384,
                                           h_c, nullptr, nullptr, nullptr, 0);
    dim3 g2((rows + 127) / 128, 1);
    gemm_kernel<1><<<g2, 256, 0, stream>>>(h_c, ew2t, eb2, rows, 384, 128,
                                           nullptr, edge + (size_t)r0 * 128,
                                           out_edge + (size_t)r0 * 128,
                                           use_eh ? e_h + (size_t)r0 * 128 : nullptr, use_eh);
  }

  // ---- scatter ----
  scatter_kernel<<<(NNZV * 64) / 256, 256, 0, stream>>>(
      e2n_r, e2n_c, e2n_v, e_h, out_edge, edge, agg, use_eh);

  // ---- node path (chunked) ----
  for (long r0 = 0; r0 < N_NODE; r0 += chn) {
    int rows = (int)((N_NODE - r0) < chn ? (N_NODE - r0) : chn);
    ln_node_kernel<<<(rows + 3) / 4, 256, 0, stream>>>(
        node + (size_t)r0 * 128, agg + (size_t)r0 * 128, n2g, n2b, xn_c, rows);
    dim3 g1((rows + 127) / 128, 2);
    gemm_kernel<0><<<g1, 256, 0, stream>>>(xn_c, nw1t, nb1, rows, 256, 256,
                                           hn_c, nullptr, nullptr, nullptr, 0);
    dim3 g2((rows + 127) / 128, 1);
    gemm_kernel<2><<<g2, 256, 0, stream>>>(hn_c, nw2t, nb2, rows, 256, 128,
                                           nullptr, node + (size_t)r0 * 128,
                                           out_node + (size_t)r0 * 128, nullptr, 0);
  }
}

// Round 3
// 611.947 us; speedup vs baseline: 1.9166x; 1.2224x over previous
//
#include <hip/hip_runtime.h>
#include <hip/hip_fp16.h>

typedef unsigned short u16;
typedef unsigned int u32;

#define N_NODE 50000
#define N_EDGE 250000
#define NNZV   500000

typedef __attribute__((ext_vector_type(8))) __bf16 bf16x8;
typedef __attribute__((ext_vector_type(4))) float f32x4;

static __device__ __forceinline__ u16 f2bf(float f) {
  union { float f; u32 u; } cv; cv.f = f;
  u32 u = cv.u;
  return (u16)((u + 0x7FFFu + ((u >> 16) & 1u)) >> 16);
}

static __device__ __forceinline__ float gelu_f(float x) {
  return 0.5f * x * (1.0f + erff(x * 0.70710678118654752f));
}

// async global->LDS: LDS dst = wave-uniform base + lane*16B, src per-lane
static __device__ __forceinline__ void gload16(const u16* g, u16* l) {
  __builtin_amdgcn_global_load_lds(
      (const __attribute__((address_space(1))) void*)g,
      (__attribute__((address_space(3))) void*)l,
      16, 0, 0);
}

// weights [in=K][out=N] f32 -> slab layout [K/32][N][32] bf16
__global__ void wprep_kernel(const float* __restrict__ in, u16* __restrict__ out,
                             int K, int N) {
  int idx = blockIdx.x * 256 + threadIdx.x;
  if (idx < K * N) {
    int k = idx / N, n = idx % N;
    out[(size_t)(k >> 5) * N * 32 + (size_t)n * 32 + (k & 31)] = f2bf(in[(size_t)k * N + n]);
  }
}

// ==================== fused edge MLP =========================================
// 64 rows/block, 4 waves (2x2): wave tile 32 rows x 192 cols (gemm1), 32x64 (gemm2)
// LDS: xh = x (64x384 bf16, XOR-swizzled 16B slots), bs = weight K-slab
__global__ __launch_bounds__(256, 2) void edge_fused_kernel(
    const float* __restrict__ node, const float* __restrict__ edge,
    const int* __restrict__ edgeIdx,
    const float* __restrict__ lng, const float* __restrict__ lnb,
    const u16* __restrict__ w1s, const float* __restrict__ b1,
    const u16* __restrict__ w2s, const float* __restrict__ b2,
    __half* __restrict__ e_h, float* __restrict__ out_edge, int store_eh) {
  const int lane = threadIdx.x & 63, wid = threadIdx.x >> 6;
  const int wm = wid >> 1, wn = wid & 1;
  const int l15 = lane & 15, gq = lane >> 4;
  const int row0 = blockIdx.x * 64;

  __shared__ __align__(16) u16 xh[64 * 48 * 8];   // 48 KB: row*48 slots of 16B
  __shared__ __align__(16) u16 bs[384 * 32];      // 24 KB

  // ---- LN + gather: wave handles 16 rows ----
  float ga[6], be[6];
#pragma unroll
  for (int s = 0; s < 3; ++s) {
    float2 g2 = *(const float2*)&lng[s * 128 + 2 * lane];
    float2 b2v = *(const float2*)&lnb[s * 128 + 2 * lane];
    ga[2 * s] = g2.x; ga[2 * s + 1] = g2.y;
    be[2 * s] = b2v.x; be[2 * s + 1] = b2v.y;
  }
#pragma unroll 2
  for (int t = 0; t < 16; ++t) {
    int lr = wid * 16 + t;
    int gi = row0 + lr; if (gi >= N_EDGE) gi = N_EDGE - 1;
    int ia = edgeIdx[2 * gi], ib = edgeIdx[2 * gi + 1];
    float2 v0 = *(const float2*)&edge[(size_t)gi * 128 + 2 * lane];
    float2 v1 = *(const float2*)&node[(size_t)ia * 128 + 2 * lane];
    float2 v2 = *(const float2*)&node[(size_t)ib * 128 + 2 * lane];
    float s  = v0.x + v0.y + v1.x + v1.y + v2.x + v2.y;
    float ss = v0.x*v0.x + v0.y*v0.y + v1.x*v1.x + v1.y*v1.y + v2.x*v2.x + v2.y*v2.y;
#pragma unroll
    for (int m = 1; m < 64; m <<= 1) { s += __shfl_xor(s, m); ss += __shfl_xor(ss, m); }
    float mean = s * (1.0f / 384.0f);
    float var  = ss * (1.0f / 384.0f) - mean * mean;
    float rstd = rsqrtf(var + 1e-5f);
    float2 vv[3] = {v0, v1, v2};
#pragma unroll
    for (int sg = 0; sg < 3; ++sg) {
      float y0 = (vv[sg].x - mean) * rstd * ga[2 * sg]     + be[2 * sg];
      float y1 = (vv[sg].y - mean) * rstd * ga[2 * sg + 1] + be[2 * sg + 1];
      u32 p = (u32)f2bf(y0) | ((u32)f2bf(y1) << 16);
      int s16 = sg * 16 + (lane >> 2);
      *(u32*)&xh[(lr * 48 + (s16 ^ (lr & 7))) * 8 + (lane & 3) * 2] = p;
    }
  }

  // ---- gemm1: y1[64x384] = x @ W1, W1 streamed in K-slabs of 32 ----
  f32x4 acc1[2][12];
#pragma unroll
  for (int nt = 0; nt < 12; ++nt) {
    float bv = b1[wn * 192 + nt * 16 + l15];
    acc1[0][nt] = (f32x4){bv, bv, bv, bv};
    acc1[1][nt] = (f32x4){bv, bv, bv, bv};
  }
  const int axor = l15 & 7;
  const int aoff0 = (wm * 32 + l15) * 48 * 8;
  const int aoff1 = (wm * 32 + 16 + l15) * 48 * 8;
  __syncthreads();

  for (int ks = 0; ks < 12; ++ks) {
    {
      const u16* src = w1s + ((size_t)ks * 384 + wid * 96) * 32 + lane * 8;
      u16* dst = &bs[(wid * 96) * 32];
#pragma unroll
      for (int t = 0; t < 6; ++t) gload16(src + t * 512, dst + t * 512);
    }
    __syncthreads();
    int asl = ((ks * 4 + gq) ^ axor) * 8;
    bf16x8 a0 = *(const bf16x8*)&xh[aoff0 + asl];
    bf16x8 a1 = *(const bf16x8*)&xh[aoff1 + asl];
#pragma unroll
    for (int nt = 0; nt < 12; ++nt) {
      bf16x8 bb = *(const bf16x8*)&bs[(wn * 192 + nt * 16 + l15) * 32 + gq * 8];
      acc1[0][nt] = __builtin_amdgcn_mfma_f32_16x16x32_bf16(a0, bb, acc1[0][nt], 0, 0, 0);
      acc1[1][nt] = __builtin_amdgcn_mfma_f32_16x16x32_bf16(a1, bb, acc1[1][nt], 0, 0, 0);
    }
    __syncthreads();
  }

  // ---- gelu -> h overwrites xh (same swizzle; all x-reads done at last barrier) ----
#pragma unroll
  for (int m = 0; m < 2; ++m)
#pragma unroll
    for (int nt = 0; nt < 12; ++nt)
#pragma unroll
      for (int j = 0; j < 4; ++j) {
        int r = wm * 32 + m * 16 + gq * 4 + j;
        int col = wn * 192 + nt * 16 + l15;
        xh[(r * 48 + ((col >> 3) ^ (r & 7))) * 8 + (l15 & 7)] = f2bf(gelu_f(acc1[m][nt][j]));
      }

  // ---- gemm2: y2[64x128] = h @ W2 ----
  f32x4 acc2[2][4];
#pragma unroll
  for (int nt = 0; nt < 4; ++nt) {
    float bv = b2[wn * 64 + nt * 16 + l15];
    acc2[0][nt] = (f32x4){bv, bv, bv, bv};
    acc2[1][nt] = (f32x4){bv, bv, bv, bv};
  }
  for (int ks = 0; ks < 12; ++ks) {
    {
      const u16* src = w2s + ((size_t)ks * 128 + wid * 32) * 32 + lane * 8;
      u16* dst = &bs[(wid * 32) * 32];
      gload16(src, dst);
      gload16(src + 512, dst + 512);
    }
    __syncthreads();   // orders h-writes (first iter) + staging
    int asl = ((ks * 4 + gq) ^ axor) * 8;
    bf16x8 a0 = *(const bf16x8*)&xh[aoff0 + asl];
    bf16x8 a1 = *(const bf16x8*)&xh[aoff1 + asl];
#pragma unroll
    for (int nt = 0; nt < 4; ++nt) {
      bf16x8 bb = *(const bf16x8*)&bs[(wn * 64 + nt * 16 + l15) * 32 + gq * 8];
      acc2[0][nt] = __builtin_amdgcn_mfma_f32_16x16x32_bf16(a0, bb, acc2[0][nt], 0, 0, 0);
      acc2[1][nt] = __builtin_amdgcn_mfma_f32_16x16x32_bf16(a1, bb, acc2[1][nt], 0, 0, 0);
    }
    __syncthreads();
  }

  // ---- epilogue ----
#pragma unroll
  for (int m = 0; m < 2; ++m)
#pragma unroll
    for (int nt = 0; nt < 4; ++nt)
#pragma unroll
      for (int j = 0; j < 4; ++j) {
        int r = row0 + wm * 32 + m * 16 + gq * 4 + j;
        if (r < N_EDGE) {
          int col = wn * 64 + nt * 16 + l15;
          __half hv = __float2half(acc2[m][nt][j]);
          if (store_eh) e_h[(size_t)r * 128 + col] = hv;
          out_edge[(size_t)r * 128 + col] = edge[(size_t)r * 128 + col] + __half2float(hv);
        }
      }
}

// ==================== fused node MLP =========================================
__global__ __launch_bounds__(256, 3) void node_fused_kernel(
    const float* __restrict__ node, const __half* __restrict__ agg,
    const float* __restrict__ lng, const float* __restrict__ lnb,
    const u16* __restrict__ w1s, const float* __restrict__ b1,
    const u16* __restrict__ w2s, const float* __restrict__ b2,
    float* __restrict__ out_node) {
  const int lane = threadIdx.x & 63, wid = threadIdx.x >> 6;
  const int wm = wid >> 1, wn = wid & 1;
  const int l15 = lane & 15, gq = lane >> 4;
  const int row0 = blockIdx.x * 64;

  __shared__ __align__(16) u16 xh[64 * 32 * 8];   // 32 KB
  __shared__ __align__(16) u16 bs[256 * 32];      // 16 KB

  float ga[4], be[4];
#pragma unroll
  for (int s = 0; s < 2; ++s) {
    float2 g2 = *(const float2*)&lng[s * 128 + 2 * lane];
    float2 b2v = *(const float2*)&lnb[s * 128 + 2 * lane];
    ga[2 * s] = g2.x; ga[2 * s + 1] = g2.y;
    be[2 * s] = b2v.x; be[2 * s + 1] = b2v.y;
  }
#pragma unroll 2
  for (int t = 0; t < 16; ++t) {
    int lr = wid * 16 + t;
    int gi = row0 + lr; if (gi >= N_NODE) gi = N_NODE - 1;
    float2 v0 = *(const float2*)&node[(size_t)gi * 128 + 2 * lane];
    float2 v1 = __half22float2(*(const __half2*)&agg[(size_t)gi * 128 + 2 * lane]);
    float s  = v0.x + v0.y + v1.x + v1.y;
    float ss = v0.x*v0.x + v0.y*v0.y + v1.x*v1.x + v1.y*v1.y;
#pragma unroll
    for (int m = 1; m < 64; m <<= 1) { s += __shfl_xor(s, m); ss += __shfl_xor(ss, m); }
    float mean = s * (1.0f / 256.0f);
    float var  = ss * (1.0f / 256.0f) - mean * mean;
    float rstd = rsqrtf(var + 1e-5f);
    float2 vv[2] = {v0, v1};
#pragma unroll
    for (int sg = 0; sg < 2; ++sg) {
      float y0 = (vv[sg].x - mean) * rstd * ga[2 * sg]     + be[2 * sg];
      float y1 = (vv[sg].y - mean) * rstd * ga[2 * sg + 1] + be[2 * sg + 1];
      u32 p = (u32)f2bf(y0) | ((u32)f2bf(y1) << 16);
      int s16 = sg * 16 + (lane >> 2);
      *(u32*)&xh[(lr * 32 + (s16 ^ (lr & 7))) * 8 + (lane & 3) * 2] = p;
    }
  }

  f32x4 acc1[2][8];
#pragma unroll
  for (int nt = 0; nt < 8; ++nt) {
    float bv = b1[wn * 128 + nt * 16 + l15];
    acc1[0][nt] = (f32x4){bv, bv, bv, bv};
    acc1[1][nt] = (f32x4){bv, bv, bv, bv};
  }
  const int axor = l15 & 7;
  const int aoff0 = (wm * 32 + l15) * 32 * 8;
  const int aoff1 = (wm * 32 + 16 + l15) * 32 * 8;
  __syncthreads();

  for (int ks = 0; ks < 8; ++ks) {
    {
      const u16* src = w1s + ((size_t)ks * 256 + wid * 64) * 32 + lane * 8;
      u16* dst = &bs[(wid * 64) * 32];
#pragma unroll
      for (int t = 0; t < 4; ++t) gload16(src + t * 512, dst + t * 512);
    }
    __syncthreads();
    int asl = ((ks * 4 + gq) ^ axor) * 8;
    bf16x8 a0 = *(const bf16x8*)&xh[aoff0 + asl];
    bf16x8 a1 = *(const bf16x8*)&xh[aoff1 + asl];
#pragma unroll
    for (int nt = 0; nt < 8; ++nt) {
      bf16x8 bb = *(const bf16x8*)&bs[(wn * 128 + nt * 16 + l15) * 32 + gq * 8];
      acc1[0][nt] = __builtin_amdgcn_mfma_f32_16x16x32_bf16(a0, bb, acc1[0][nt], 0, 0, 0);
      acc1[1][nt] = __builtin_amdgcn_mfma_f32_16x16x32_bf16(a1, bb, acc1[1][nt], 0, 0, 0);
    }
    __syncthreads();
  }

#pragma unroll
  for (int m = 0; m < 2; ++m)
#pragma unroll
    for (int nt = 0; nt < 8; ++nt)
#pragma unroll
      for (int j = 0; j < 4; ++j) {
        int r = wm * 32 + m * 16 + gq * 4 + j;
        int col = wn * 128 + nt * 16 + l15;
        xh[(r * 32 + ((col >> 3) ^ (r & 7))) * 8 + (l15 & 7)] = f2bf(gelu_f(acc1[m][nt][j]));
      }

  f32x4 acc2[2][4];
#pragma unroll
  for (int nt = 0; nt < 4; ++nt) {
    float bv = b2[wn * 64 + nt * 16 + l15];
    acc2[0][nt] = (f32x4){bv, bv, bv, bv};
    acc2[1][nt] = (f32x4){bv, bv, bv, bv};
  }
  for (int ks = 0; ks < 8; ++ks) {
    {
      const u16* src = w2s + ((size_t)ks * 128 + wid * 32) * 32 + lane * 8;
      u16* dst = &bs[(wid * 32) * 32];
      gload16(src, dst);
      gload16(src + 512, dst + 512);
    }
    __syncthreads();
    int asl = ((ks * 4 + gq) ^ axor) * 8;
    bf16x8 a0 = *(const bf16x8*)&xh[aoff0 + asl];
    bf16x8 a1 = *(const bf16x8*)&xh[aoff1 + asl];
#pragma unroll
    for (int nt = 0; nt < 4; ++nt) {
      bf16x8 bb = *(const bf16x8*)&bs[(wn * 64 + nt * 16 + l15) * 32 + gq * 8];
      acc2[0][nt] = __builtin_amdgcn_mfma_f32_16x16x32_bf16(a0, bb, acc2[0][nt], 0, 0, 0);
      acc2[1][nt] = __builtin_amdgcn_mfma_f32_16x16x32_bf16(a1, bb, acc2[1][nt], 0, 0, 0);
    }
    __syncthreads();
  }

#pragma unroll
  for (int m = 0; m < 2; ++m)
#pragma unroll
    for (int nt = 0; nt < 4; ++nt)
#pragma unroll
      for (int j = 0; j < 4; ++j) {
        int r = row0 + wm * 32 + m * 16 + gq * 4 + j;
        if (r < N_NODE) {
          int col = wn * 64 + nt * 16 + l15;
          out_node[(size_t)r * 128 + col] = node[(size_t)r * 128 + col] + acc2[m][nt][j];
        }
      }
}

// ---------------- scatter: agg[row] += fp16(e[col] * val), pk fp16 atomics ----
__global__ __launch_bounds__(256) void scatter_kernel(
    const int* __restrict__ rows, const int* __restrict__ cols,
    const float* __restrict__ vals,
    const __half* __restrict__ e_h,
    const float* __restrict__ out_edge, const float* __restrict__ edge,
    __half* __restrict__ agg, int use_eh) {
  long t = (long)blockIdx.x * 256 + threadIdx.x;
  int k = (int)(t >> 6);
  int l = (int)(t & 63);
  int r = rows[k], c = cols[k];
  float v = vals[k];
  __half2 h2;
  if (use_eh) {
    h2 = *(const __half2*)&e_h[(size_t)c * 128 + 2 * l];
  } else {
    size_t o = (size_t)c * 128 + 2 * l;
    float2 eo = *(const float2*)&out_edge[o];
    float2 e0 = *(const float2*)&edge[o];
    h2 = __floats2half2_rn(eo.x - e0.x, eo.y - e0.y);
  }
  h2 = __hmul2(h2, __float2half2_rn(v));
  unsafeAtomicAdd((__half2*)&agg[(size_t)r * 128 + 2 * l], h2);
}

extern "C" void kernel_launch(void* const* d_in, const int* in_sizes, int n_in,
                              void* d_out, int out_size, void* d_ws, size_t ws_size,
                              hipStream_t stream) {
  (void)in_sizes; (void)n_in; (void)out_size;
  const float* node    = (const float*)d_in[0];
  const float* edge    = (const float*)d_in[1];
  const int*   edgeIdx = (const int*)d_in[2];
  const int*   e2n_r   = (const int*)d_in[3];
  const int*   e2n_c   = (const int*)d_in[4];
  const float* e2n_v   = (const float*)d_in[5];
  const float* n1g     = (const float*)d_in[6];
  const float* n1b     = (const float*)d_in[7];
  const float* n2g     = (const float*)d_in[8];
  const float* n2b     = (const float*)d_in[9];
  const float* ew1     = (const float*)d_in[10];
  const float* eb1     = (const float*)d_in[11];
  const float* ew2     = (const float*)d_in[12];
  const float* eb2     = (const float*)d_in[13];
  const float* nw1     = (const float*)d_in[14];
  const float* nb1     = (const float*)d_in[15];
  const float* nw2     = (const float*)d_in[16];
  const float* nb2     = (const float*)d_in[17];

  float* out_node = (float*)d_out;
  float* out_edge = out_node + (size_t)N_NODE * 128;

  char* w = (char*)d_ws;
  auto alloc = [&](size_t bytes) { char* p = w; w += (bytes + 255) & ~(size_t)255; return p; };
  u16* ew1s = (u16*)alloc((size_t)384 * 384 * 2);
  u16* ew2s = (u16*)alloc((size_t)384 * 128 * 2);
  u16* nw1s = (u16*)alloc((size_t)256 * 256 * 2);
  u16* nw2s = (u16*)alloc((size_t)256 * 128 * 2);
  __half* agg = (__half*)alloc((size_t)N_NODE * 128 * 2);

  size_t used = (size_t)(w - (char*)d_ws);
  const size_t EH_BYTES = (size_t)N_EDGE * 128 * 2;   // 64 MB
  int use_eh = (ws_size >= used + EH_BYTES) ? 1 : 0;
  __half* e_h = nullptr;
  if (use_eh) e_h = (__half*)alloc(EH_BYTES);

  wprep_kernel<<<(384 * 384 + 255) / 256, 256, 0, stream>>>(ew1, ew1s, 384, 384);
  wprep_kernel<<<(384 * 128 + 255) / 256, 256, 0, stream>>>(ew2, ew2s, 384, 128);
  wprep_kernel<<<(256 * 256 + 255) / 256, 256, 0, stream>>>(nw1, nw1s, 256, 256);
  wprep_kernel<<<(256 * 128 + 255) / 256, 256, 0, stream>>>(nw2, nw2s, 256, 128);
  hipMemsetAsync(agg, 0, (size_t)N_NODE * 128 * 2, stream);

  edge_fused_kernel<<<(N_EDGE + 63) / 64, 256, 0, stream>>>(
      node, edge, edgeIdx, n1g, n1b, ew1s, eb1, ew2s, eb2, e_h, out_edge, use_eh);

  scatter_kernel<<<(NNZV * 64) / 256, 256, 0, stream>>>(
      e2n_r, e2n_c, e2n_v, e_h, out_edge, edge, agg, use_eh);

  node_fused_kernel<<<(N_NODE + 63) / 64, 256, 0, stream>>>(
      node, agg, n2g, n2b, nw1s, nb1, nw2s, nb2, out_node);
}

// Round 4
// 593.997 us; speedup vs baseline: 1.9745x; 1.0302x over previous
//
#include <hip/hip_runtime.h>
#include <hip/hip_fp16.h>

typedef unsigned short u16;
typedef unsigned int u32;

#define N_NODE 50000
#define N_EDGE 250000
#define NNZV   500000

typedef __attribute__((ext_vector_type(8))) __bf16 bf16x8;
typedef __attribute__((ext_vector_type(4))) float f32x4;

static __device__ __forceinline__ u16 f2bf(float f) {
  union { float f; u32 u; } cv; cv.f = f;
  u32 u = cv.u;
  return (u16)((u + 0x7FFFu + ((u >> 16) & 1u)) >> 16);
}

static __device__ __forceinline__ float gelu_f(float x) {
  return 0.5f * x * (1.0f + erff(x * 0.70710678118654752f));
}

// async global->LDS: LDS dst wave-uniform base (+ lane*16B by HW), src per-lane
static __device__ __forceinline__ void gload16(const u16* g, u16* l) {
  __builtin_amdgcn_global_load_lds(
      (const __attribute__((address_space(1))) void*)g,
      (__attribute__((address_space(3))) void*)l,
      16, 0, 0);
}

// weights [in=K][out=N] f32 -> slab layout [K/32][N][4 chunks of 8, XOR-swizzled]
// phys chunk p holds logical chunk g = p ^ ((n>>1)&3)  (kills ds_read bank conflicts)
__global__ void wprep_kernel(const float* __restrict__ in, u16* __restrict__ out,
                             int K, int N) {
  int idx = blockIdx.x * 256 + threadIdx.x;
  if (idx < K * N) {
    int k = idx / N, n = idx % N;
    int ks = k >> 5, g = (k >> 3) & 3, e = k & 7;
    int p = g ^ ((n >> 1) & 3);
    out[((size_t)ks * N + n) * 32 + p * 8 + e] = f2bf(in[(size_t)k * N + n]);
  }
}

// ==================== fused edge MLP =========================================
// 128 rows/block, 512 threads (8 waves). gemm1 wave tile 64x96, gemm2 64x32.
// LDS: xh 96KB (x then h, slot-XOR swizzle), bs dbuf 2x24KB.
__global__ __launch_bounds__(512, 2) void edge_fused_kernel(
    const float* __restrict__ node, const float* __restrict__ edge,
    const int* __restrict__ edgeIdx,
    const float* __restrict__ lng, const float* __restrict__ lnb,
    const u16* __restrict__ w1s, const float* __restrict__ b1,
    const u16* __restrict__ w2s, const float* __restrict__ b2,
    __half* __restrict__ e_h, float* __restrict__ out_edge, int store_eh) {
  const int lane = threadIdx.x & 63, wid = threadIdx.x >> 6;   // 0..7
  const int l15 = lane & 15, gq = lane >> 4;
  const int row0 = blockIdx.x * 128;

  __shared__ __align__(16) u16 xh[128 * 48 * 8];   // 96 KB, row pitch 384 u16
  __shared__ __align__(16) u16 bs[2][12288];       // 2 x 24 KB

  // ---- stage W1 slab 0 -> bs[0] (hides under LN) ----
  {
    const u16* src = w1s + (size_t)(wid * 64 + lane) * 8;
#pragma unroll
    for (int r = 0; r < 3; ++r)
      gload16(src + r * 4096, &bs[0][(r * 512 + wid * 64) * 8]);
  }

  // ---- LN + gather: wave handles 16 rows ----
  float ga[6], be[6];
#pragma unroll
  for (int s = 0; s < 3; ++s) {
    float2 g2 = *(const float2*)&lng[s * 128 + 2 * lane];
    float2 b2v = *(const float2*)&lnb[s * 128 + 2 * lane];
    ga[2 * s] = g2.x; ga[2 * s + 1] = g2.y;
    be[2 * s] = b2v.x; be[2 * s + 1] = b2v.y;
  }
#pragma unroll 2
  for (int t = 0; t < 16; ++t) {
    int lr = wid * 16 + t;
    int gi = row0 + lr; if (gi >= N_EDGE) gi = N_EDGE - 1;
    int ia = edgeIdx[2 * gi], ib = edgeIdx[2 * gi + 1];
    float2 v0 = *(const float2*)&edge[(size_t)gi * 128 + 2 * lane];
    float2 v1 = *(const float2*)&node[(size_t)ia * 128 + 2 * lane];
    float2 v2 = *(const float2*)&node[(size_t)ib * 128 + 2 * lane];
    float s  = v0.x + v0.y + v1.x + v1.y + v2.x + v2.y;
    float ss = v0.x*v0.x + v0.y*v0.y + v1.x*v1.x + v1.y*v1.y + v2.x*v2.x + v2.y*v2.y;
#pragma unroll
    for (int m = 1; m < 64; m <<= 1) { s += __shfl_xor(s, m); ss += __shfl_xor(ss, m); }
    float mean = s * (1.0f / 384.0f);
    float var  = ss * (1.0f / 384.0f) - mean * mean;
    float rstd = rsqrtf(var + 1e-5f);
    float2 vv[3] = {v0, v1, v2};
#pragma unroll
    for (int sg = 0; sg < 3; ++sg) {
      float y0 = (vv[sg].x - mean) * rstd * ga[2 * sg]     + be[2 * sg];
      float y1 = (vv[sg].y - mean) * rstd * ga[2 * sg + 1] + be[2 * sg + 1];
      u32 p = (u32)f2bf(y0) | ((u32)f2bf(y1) << 16);
      int s16 = sg * 16 + (lane >> 2);
      *(u32*)&xh[(lr * 48 + (s16 ^ (lr & 7))) * 8 + (lane & 3) * 2] = p;
    }
  }

  // ---- gemm1: wave (wm,wn) -> rows wm*64..+63, cols wn*96..+95 ----
  const int wm = wid >> 2, wn = wid & 3;
  f32x4 acc1[4][6];
#pragma unroll
  for (int nt = 0; nt < 6; ++nt) {
    float bv = b1[wn * 96 + nt * 16 + l15];
#pragma unroll
    for (int m = 0; m < 4; ++m) acc1[m][nt] = (f32x4){bv, bv, bv, bv};
  }
  int boff1[6];
#pragma unroll
  for (int nt = 0; nt < 6; ++nt) {
    int n = wn * 96 + nt * 16 + l15;
    boff1[nt] = n * 32 + (gq ^ ((n >> 1) & 3)) * 8;
  }
  int aoff[4];
#pragma unroll
  for (int m = 0; m < 4; ++m) aoff[m] = (wm * 64 + m * 16 + l15) * 384;
  const int axr = l15 & 7;
  __syncthreads();

  for (int ks = 0; ks < 12; ++ks) {
    const int buf = ks & 1;
    if (ks < 11) {
      const u16* src = w1s + (size_t)(ks + 1) * 12288 + (size_t)(wid * 64 + lane) * 8;
#pragma unroll
      for (int r = 0; r < 3; ++r)
        gload16(src + r * 4096, &bs[buf ^ 1][(r * 512 + wid * 64) * 8]);
    }
    const int asl = ((ks * 4 + gq) ^ axr) * 8;
    bf16x8 a[4], bb[6];
#pragma unroll
    for (int m = 0; m < 4; ++m) a[m] = *(const bf16x8*)&xh[aoff[m] + asl];
#pragma unroll
    for (int nt = 0; nt < 6; ++nt) bb[nt] = *(const bf16x8*)&bs[buf][boff1[nt]];
#pragma unroll
    for (int m = 0; m < 4; ++m)
#pragma unroll
      for (int nt = 0; nt < 6; ++nt)
        acc1[m][nt] = __builtin_amdgcn_mfma_f32_16x16x32_bf16(a[m], bb[nt], acc1[m][nt], 0, 0, 0);
    __syncthreads();
  }

  // ---- stage W2 slab 0 (hides under gelu), gelu -> h overwrites xh ----
  {
    const u16* src = w2s + (size_t)(wid * 64 + lane) * 8;
    gload16(src, &bs[0][(wid * 64) * 8]);
  }
#pragma unroll
  for (int m = 0; m < 4; ++m)
#pragma unroll
    for (int nt = 0; nt < 6; ++nt)
#pragma unroll
      for (int j = 0; j < 4; ++j) {
        int r = wm * 64 + m * 16 + gq * 4 + j;
        int col = wn * 96 + nt * 16 + l15;
        xh[r * 384 + (((col >> 3) ^ (r & 7)) * 8) + (col & 7)] = f2bf(gelu_f(acc1[m][nt][j]));
      }
  __syncthreads();

  // ---- gemm2: wave (wm2,wn2) -> rows wm2*64..+63, cols wn2*32..+31 ----
  const int wm2 = wid >> 2, wn2 = wid & 3;
  f32x4 acc2[4][2];
#pragma unroll
  for (int nt = 0; nt < 2; ++nt) {
    float bv = b2[wn2 * 32 + nt * 16 + l15];
#pragma unroll
    for (int m = 0; m < 4; ++m) acc2[m][nt] = (f32x4){bv, bv, bv, bv};
  }
  int boff2[2];
#pragma unroll
  for (int nt = 0; nt < 2; ++nt) {
    int n = wn2 * 32 + nt * 16 + l15;
    boff2[nt] = n * 32 + (gq ^ ((n >> 1) & 3)) * 8;
  }

  for (int ks = 0; ks < 12; ++ks) {
    const int buf = ks & 1;
    if (ks < 11) {
      const u16* src = w2s + (size_t)(ks + 1) * 4096 + (size_t)(wid * 64 + lane) * 8;
      gload16(src, &bs[buf ^ 1][(wid * 64) * 8]);
    }
    const int asl = ((ks * 4 + gq) ^ axr) * 8;
    bf16x8 a[4], bb[2];
#pragma unroll
    for (int m = 0; m < 4; ++m) a[m] = *(const bf16x8*)&xh[aoff[m] + asl];
#pragma unroll
    for (int nt = 0; nt < 2; ++nt) bb[nt] = *(const bf16x8*)&bs[buf][boff2[nt]];
#pragma unroll
    for (int m = 0; m < 4; ++m)
#pragma unroll
      for (int nt = 0; nt < 2; ++nt)
        acc2[m][nt] = __builtin_amdgcn_mfma_f32_16x16x32_bf16(a[m], bb[nt], acc2[m][nt], 0, 0, 0);
    __syncthreads();
  }

  // ---- epilogue ----
#pragma unroll
  for (int m = 0; m < 4; ++m)
#pragma unroll
    for (int nt = 0; nt < 2; ++nt)
#pragma unroll
      for (int j = 0; j < 4; ++j) {
        int r = row0 + wm2 * 64 + m * 16 + gq * 4 + j;
        if (r < N_EDGE) {
          int col = wn2 * 32 + nt * 16 + l15;
          __half hv = __float2half(acc2[m][nt][j]);
          if (store_eh) e_h[(size_t)r * 128 + col] = hv;
          out_edge[(size_t)r * 128 + col] = edge[(size_t)r * 128 + col] + __half2float(hv);
        }
      }
}

// ==================== fused node MLP =========================================
// 64 rows/block, 256 threads (4 waves). gemm1 wave 64x64, gemm2 64x32. dbuf.
__global__ __launch_bounds__(256, 2) void node_fused_kernel(
    const float* __restrict__ node, const __half* __restrict__ agg,
    const float* __restrict__ lng, const float* __restrict__ lnb,
    const u16* __restrict__ w1s, const float* __restrict__ b1,
    const u16* __restrict__ w2s, const float* __restrict__ b2,
    float* __restrict__ out_node) {
  const int lane = threadIdx.x & 63, wid = threadIdx.x >> 6;   // 0..3
  const int l15 = lane & 15, gq = lane >> 4;
  const int row0 = blockIdx.x * 64;

  __shared__ __align__(16) u16 xh[64 * 32 * 8];   // 32 KB, row pitch 256 u16
  __shared__ __align__(16) u16 bs[2][8192];       // 2 x 16 KB

  // stage W1 slab 0 (8192 u16, 4 rounds of 2048)
  {
    const u16* src = w1s + (size_t)(wid * 64 + lane) * 8;
#pragma unroll
    for (int r = 0; r < 4; ++r)
      gload16(src + r * 2048, &bs[0][(r * 256 + wid * 64) * 8]);
  }

  float ga[4], be[4];
#pragma unroll
  for (int s = 0; s < 2; ++s) {
    float2 g2 = *(const float2*)&lng[s * 128 + 2 * lane];
    float2 b2v = *(const float2*)&lnb[s * 128 + 2 * lane];
    ga[2 * s] = g2.x; ga[2 * s + 1] = g2.y;
    be[2 * s] = b2v.x; be[2 * s + 1] = b2v.y;
  }
#pragma unroll 2
  for (int t = 0; t < 16; ++t) {
    int lr = wid * 16 + t;
    int gi = row0 + lr; if (gi >= N_NODE) gi = N_NODE - 1;
    float2 v0 = *(const float2*)&node[(size_t)gi * 128 + 2 * lane];
    float2 v1 = __half22float2(*(const __half2*)&agg[(size_t)gi * 128 + 2 * lane]);
    float s  = v0.x + v0.y + v1.x + v1.y;
    float ss = v0.x*v0.x + v0.y*v0.y + v1.x*v1.x + v1.y*v1.y;
#pragma unroll
    for (int m = 1; m < 64; m <<= 1) { s += __shfl_xor(s, m); ss += __shfl_xor(ss, m); }
    float mean = s * (1.0f / 256.0f);
    float var  = ss * (1.0f / 256.0f) - mean * mean;
    float rstd = rsqrtf(var + 1e-5f);
    float2 vv[2] = {v0, v1};
#pragma unroll
    for (int sg = 0; sg < 2; ++sg) {
      float y0 = (vv[sg].x - mean) * rstd * ga[2 * sg]     + be[2 * sg];
      float y1 = (vv[sg].y - mean) * rstd * ga[2 * sg + 1] + be[2 * sg + 1];
      u32 p = (u32)f2bf(y0) | ((u32)f2bf(y1) << 16);
      int s16 = sg * 16 + (lane >> 2);
      *(u32*)&xh[(lr * 32 + (s16 ^ (lr & 7))) * 8 + (lane & 3) * 2] = p;
    }
  }

  // gemm1: wave wn -> all 64 rows, cols wn*64..+63
  const int wn = wid;
  f32x4 acc1[4][4];
#pragma unroll
  for (int nt = 0; nt < 4; ++nt) {
    float bv = b1[wn * 64 + nt * 16 + l15];
#pragma unroll
    for (int m = 0; m < 4; ++m) acc1[m][nt] = (f32x4){bv, bv, bv, bv};
  }
  int boff1[4];
#pragma unroll
  for (int nt = 0; nt < 4; ++nt) {
    int n = wn * 64 + nt * 16 + l15;
    boff1[nt] = n * 32 + (gq ^ ((n >> 1) & 3)) * 8;
  }
  int aoff[4];
#pragma unroll
  for (int m = 0; m < 4; ++m) aoff[m] = (m * 16 + l15) * 256;
  const int axr = l15 & 7;
  __syncthreads();

  for (int ks = 0; ks < 8; ++ks) {
    const int buf = ks & 1;
    if (ks < 7) {
      const u16* src = w1s + (size_t)(ks + 1) * 8192 + (size_t)(wid * 64 + lane) * 8;
#pragma unroll
      for (int r = 0; r < 4; ++r)
        gload16(src + r * 2048, &bs[buf ^ 1][(r * 256 + wid * 64) * 8]);
    }
    const int asl = ((ks * 4 + gq) ^ axr) * 8;
    bf16x8 a[4], bb[4];
#pragma unroll
    for (int m = 0; m < 4; ++m) a[m] = *(const bf16x8*)&xh[aoff[m] + asl];
#pragma unroll
    for (int nt = 0; nt < 4; ++nt) bb[nt] = *(const bf16x8*)&bs[buf][boff1[nt]];
#pragma unroll
    for (int m = 0; m < 4; ++m)
#pragma unroll
      for (int nt = 0; nt < 4; ++nt)
        acc1[m][nt] = __builtin_amdgcn_mfma_f32_16x16x32_bf16(a[m], bb[nt], acc1[m][nt], 0, 0, 0);
    __syncthreads();
  }

  // stage W2 slab 0 (4096 u16, 2 rounds), gelu -> h
  {
    const u16* src = w2s + (size_t)(wid * 64 + lane) * 8;
#pragma unroll
    for (int r = 0; r < 2; ++r)
      gload16(src + r * 2048, &bs[0][(r * 256 + wid * 64) * 8]);
  }
#pragma unroll
  for (int m = 0; m < 4; ++m)
#pragma unroll
    for (int nt = 0; nt < 4; ++nt)
#pragma unroll
      for (int j = 0; j < 4; ++j) {
        int r = m * 16 + gq * 4 + j;
        int col = wn * 64 + nt * 16 + l15;
        xh[r * 256 + (((col >> 3) ^ (r & 7)) * 8) + (col & 7)] = f2bf(gelu_f(acc1[m][nt][j]));
      }
  __syncthreads();

  // gemm2: wave wn2 -> cols wn2*32..+31
  const int wn2 = wid;
  f32x4 acc2[4][2];
#pragma unroll
  for (int nt = 0; nt < 2; ++nt) {
    float bv = b2[wn2 * 32 + nt * 16 + l15];
#pragma unroll
    for (int m = 0; m < 4; ++m) acc2[m][nt] = (f32x4){bv, bv, bv, bv};
  }
  int boff2[2];
#pragma unroll
  for (int nt = 0; nt < 2; ++nt) {
    int n = wn2 * 32 + nt * 16 + l15;
    boff2[nt] = n * 32 + (gq ^ ((n >> 1) & 3)) * 8;
  }

  for (int ks = 0; ks < 8; ++ks) {
    const int buf = ks & 1;
    if (ks < 7) {
      const u16* src = w2s + (size_t)(ks + 1) * 4096 + (size_t)(wid * 64 + lane) * 8;
#pragma unroll
      for (int r = 0; r < 2; ++r)
        gload16(src + r * 2048, &bs[buf ^ 1][(r * 256 + wid * 64) * 8]);
    }
    const int asl = ((ks * 4 + gq) ^ axr) * 8;
    bf16x8 a[4], bb[2];
#pragma unroll
    for (int m = 0; m < 4; ++m) a[m] = *(const bf16x8*)&xh[aoff[m] + asl];
#pragma unroll
    for (int nt = 0; nt < 2; ++nt) bb[nt] = *(const bf16x8*)&bs[buf][boff2[nt]];
#pragma unroll
    for (int m = 0; m < 4; ++m)
#pragma unroll
      for (int nt = 0; nt < 2; ++nt)
        acc2[m][nt] = __builtin_amdgcn_mfma_f32_16x16x32_bf16(a[m], bb[nt], acc2[m][nt], 0, 0, 0);
    __syncthreads();
  }

#pragma unroll
  for (int m = 0; m < 4; ++m)
#pragma unroll
    for (int nt = 0; nt < 2; ++nt)
#pragma unroll
      for (int j = 0; j < 4; ++j) {
        int r = row0 + m * 16 + gq * 4 + j;
        if (r < N_NODE) {
          int col = wn2 * 32 + nt * 16 + l15;
          out_node[(size_t)r * 128 + col] = node[(size_t)r * 128 + col] + acc2[m][nt][j];
        }
      }
}

// ---------------- scatter: agg[row] += fp16(e[col] * val), pk fp16 atomics ----
__global__ __launch_bounds__(256) void scatter_kernel(
    const int* __restrict__ rows, const int* __restrict__ cols,
    const float* __restrict__ vals,
    const __half* __restrict__ e_h,
    const float* __restrict__ out_edge, const float* __restrict__ edge,
    __half* __restrict__ agg, int use_eh) {
  long t = (long)blockIdx.x * 256 + threadIdx.x;
  int k = (int)(t >> 6);
  int l = (int)(t & 63);
  int r = rows[k], c = cols[k];
  float v = vals[k];
  __half2 h2;
  if (use_eh) {
    h2 = *(const __half2*)&e_h[(size_t)c * 128 + 2 * l];
  } else {
    size_t o = (size_t)c * 128 + 2 * l;
    float2 eo = *(const float2*)&out_edge[o];
    float2 e0 = *(const float2*)&edge[o];
    h2 = __floats2half2_rn(eo.x - e0.x, eo.y - e0.y);
  }
  h2 = __hmul2(h2, __float2half2_rn(v));
  unsafeAtomicAdd((__half2*)&agg[(size_t)r * 128 + 2 * l], h2);
}

extern "C" void kernel_launch(void* const* d_in, const int* in_sizes, int n_in,
                              void* d_out, int out_size, void* d_ws, size_t ws_size,
                              hipStream_t stream) {
  (void)in_sizes; (void)n_in; (void)out_size;
  const float* node    = (const float*)d_in[0];
  const float* edge    = (const float*)d_in[1];
  const int*   edgeIdx = (const int*)d_in[2];
  const int*   e2n_r   = (const int*)d_in[3];
  const int*   e2n_c   = (const int*)d_in[4];
  const float* e2n_v   = (const float*)d_in[5];
  const float* n1g     = (const float*)d_in[6];
  const float* n1b     = (const float*)d_in[7];
  const float* n2g     = (const float*)d_in[8];
  const float* n2b     = (const float*)d_in[9];
  const float* ew1     = (const float*)d_in[10];
  const float* eb1     = (const float*)d_in[11];
  const float* ew2     = (const float*)d_in[12];
  const float* eb2     = (const float*)d_in[13];
  const float* nw1     = (const float*)d_in[14];
  const float* nb1     = (const float*)d_in[15];
  const float* nw2     = (const float*)d_in[16];
  const float* nb2     = (const float*)d_in[17];

  float* out_node = (float*)d_out;
  float* out_edge = out_node + (size_t)N_NODE * 128;

  char* w = (char*)d_ws;
  auto alloc = [&](size_t bytes) { char* p = w; w += (bytes + 255) & ~(size_t)255; return p; };
  u16* ew1s = (u16*)alloc((size_t)384 * 384 * 2);
  u16* ew2s = (u16*)alloc((size_t)384 * 128 * 2);
  u16* nw1s = (u16*)alloc((size_t)256 * 256 * 2);
  u16* nw2s = (u16*)alloc((size_t)256 * 128 * 2);
  __half* agg = (__half*)alloc((size_t)N_NODE * 128 * 2);

  size_t used = (size_t)(w - (char*)d_ws);
  const size_t EH_BYTES = (size_t)N_EDGE * 128 * 2;   // 64 MB
  int use_eh = (ws_size >= used + EH_BYTES) ? 1 : 0;
  __half* e_h = nullptr;
  if (use_eh) e_h = (__half*)alloc(EH_BYTES);

  wprep_kernel<<<(384 * 384 + 255) / 256, 256, 0, stream>>>(ew1, ew1s, 384, 384);
  wprep_kernel<<<(384 * 128 + 255) / 256, 256, 0, stream>>>(ew2, ew2s, 384, 128);
  wprep_kernel<<<(256 * 256 + 255) / 256, 256, 0, stream>>>(nw1, nw1s, 256, 256);
  wprep_kernel<<<(256 * 128 + 255) / 256, 256, 0, stream>>>(nw2, nw2s, 256, 128);
  hipMemsetAsync(agg, 0, (size_t)N_NODE * 128 * 2, stream);

  edge_fused_kernel<<<(N_EDGE + 127) / 128, 512, 0, stream>>>(
      node, edge, edgeIdx, n1g, n1b, ew1s, eb1, ew2s, eb2, e_h, out_edge, use_eh);

  scatter_kernel<<<(NNZV * 64) / 256, 256, 0, stream>>>(
      e2n_r, e2n_c, e2n_v, e_h, out_edge, edge, agg, use_eh);

  node_fused_kernel<<<(N_NODE + 63) / 64, 256, 0, stream>>>(
      node, agg, n2g, n2b, nw1s, nb1, nw2s, nb2, out_node);
}

// Round 5
// 495.777 us; speedup vs baseline: 2.3656x; 1.1981x over previous
//
#include <hip/hip_runtime.h>
#include <hip/hip_fp16.h>

typedef unsigned short u16;
typedef unsigned int u32;

#define N_NODE 50000
#define N_EDGE 250000
#define NNZV   500000

typedef __attribute__((ext_vector_type(8))) __bf16 bf16x8;
typedef __attribute__((ext_vector_type(4))) float f32x4;

#define WAITVM(n) asm volatile("s_waitcnt vmcnt(" #n ")" ::: "memory")
#define WAITLGKM0() asm volatile("s_waitcnt lgkmcnt(0)" ::: "memory")

static __device__ __forceinline__ u16 f2bf(float f) {
  union { float f; u32 u; } cv; cv.f = f;
  u32 u = cv.u;
  return (u16)((u + 0x7FFFu + ((u >> 16) & 1u)) >> 16);
}

// exact-erf gelu via A&S 7.1.26 poly (|erf err| <= 1.5e-7), ~15 VALU ops
static __device__ __forceinline__ float gelu_f(float x) {
  float z = fabsf(x) * 0.70710678118654752f;
  float t = __builtin_amdgcn_rcpf(1.0f + 0.3275911f * z);
  float p = t * (0.254829592f + t * (-0.284496736f + t * (1.421413741f +
            t * (-1.453152027f + t * 1.061405429f))));
  float er = 1.0f - p * __expf(-z * z);
  er = copysignf(er, x);
  return 0.5f * x * (1.0f + er);
}

// async global->LDS: LDS dst wave-uniform base (+ lane*16B by HW), src per-lane
static __device__ __forceinline__ void gload16(const u16* g, u16* l) {
  __builtin_amdgcn_global_load_lds(
      (const __attribute__((address_space(1))) void*)g,
      (__attribute__((address_space(3))) void*)l,
      16, 0, 0);
}

// weights [in=K][out=N] f32 -> slab layout [K/32][N][4 chunks of 8, XOR-swizzled]
// phys chunk p holds logical chunk g = p ^ ((n>>1)&3)
__global__ void wprep_kernel(const float* __restrict__ in, u16* __restrict__ out,
                             int K, int N) {
  int idx = blockIdx.x * 256 + threadIdx.x;
  if (idx < K * N) {
    int k = idx / N, n = idx % N;
    int ks = k >> 5, g = (k >> 3) & 3, e = k & 7;
    int p = g ^ ((n >> 1) & 3);
    out[((size_t)ks * N + n) * 32 + p * 8 + e] = f2bf(in[(size_t)k * N + n]);
  }
}

// ==================== fused edge MLP =========================================
// 64 rows/block, 512 threads (8 waves). Barrier-free K-loops:
// gemm1 wave owns 48 cols, gemm2 16 cols; wave-private 3-buffer slab ring,
// counted vmcnt. LDS: xh 48KB + bs 72KB = 120KB -> 1 block/CU, 2 waves/SIMD.
__global__ __launch_bounds__(512, 2) void edge_fused_kernel(
    const float* __restrict__ node, const float* __restrict__ edge,
    const int* __restrict__ edgeIdx,
    const float* __restrict__ lng, const float* __restrict__ lnb,
    const u16* __restrict__ w1s, const float* __restrict__ b1,
    const u16* __restrict__ w2s, const float* __restrict__ b2,
    __half* __restrict__ e_h, float* __restrict__ out_edge, int store_eh) {
  const int lane = threadIdx.x & 63, wid = threadIdx.x >> 6;   // 0..7
  const int l15 = lane & 15, gq = lane >> 4;
  const int row0 = blockIdx.x * 64;

  __shared__ __align__(16) u16 xh[64 * 48 * 8];    // 48 KB, row pitch 384 u16
  __shared__ __align__(16) u16 bs[8][3][1536];     // 72 KB, wave-private rings

  // ---- gemm1 slab prefetch (slabs 0,1) before LN: stays in flight over barrier
  const u16* w1base = w1s + (size_t)(wid * 48) * 32 + (size_t)lane * 8;
#define STAGE1(ks, buf)                                         \
  { const u16* s_ = w1base + (size_t)(ks) * 12288;              \
    u16* d_ = &bs[wid][buf][0];                                 \
    gload16(s_, d_); gload16(s_ + 512, d_ + 512); gload16(s_ + 1024, d_ + 1024); }
  STAGE1(0, 0);
  STAGE1(1, 1);

  // ---- LN + gather: 8 rows/wave, batched loads then independent reduces ----
  float ga[6], be[6];
#pragma unroll
  for (int s = 0; s < 3; ++s) {
    float2 g2 = *(const float2*)&lng[s * 128 + 2 * lane];
    float2 b2v = *(const float2*)&lnb[s * 128 + 2 * lane];
    ga[2 * s] = g2.x; ga[2 * s + 1] = g2.y;
    be[2 * s] = b2v.x; be[2 * s + 1] = b2v.y;
  }
  int gi[8], ia[8], ib[8];
#pragma unroll
  for (int t = 0; t < 8; ++t) {
    int g = row0 + wid * 8 + t; if (g > N_EDGE - 1) g = N_EDGE - 1;
    gi[t] = g;
    int2 ab = *(const int2*)&edgeIdx[2 * g];
    ia[t] = ab.x; ib[t] = ab.y;
  }
  float2 v0[8], v1[8], v2[8];
#pragma unroll
  for (int t = 0; t < 8; ++t) {
    v0[t] = *(const float2*)&edge[(size_t)gi[t] * 128 + 2 * lane];
    v1[t] = *(const float2*)&node[(size_t)ia[t] * 128 + 2 * lane];
    v2[t] = *(const float2*)&node[(size_t)ib[t] * 128 + 2 * lane];
  }
#pragma unroll
  for (int t = 0; t < 8; ++t) {
    float s  = v0[t].x + v0[t].y + v1[t].x + v1[t].y + v2[t].x + v2[t].y;
    float ss = v0[t].x*v0[t].x + v0[t].y*v0[t].y + v1[t].x*v1[t].x +
               v1[t].y*v1[t].y + v2[t].x*v2[t].x + v2[t].y*v2[t].y;
#pragma unroll
    for (int m = 1; m < 64; m <<= 1) { s += __shfl_xor(s, m); ss += __shfl_xor(ss, m); }
    float mean = s * (1.0f / 384.0f);
    float var  = ss * (1.0f / 384.0f) - mean * mean;
    float rstd = rsqrtf(var + 1e-5f);
    int lr = wid * 8 + t;
    float2 vv[3] = {v0[t], v1[t], v2[t]};
#pragma unroll
    for (int sg = 0; sg < 3; ++sg) {
      float y0 = (vv[sg].x - mean) * rstd * ga[2 * sg]     + be[2 * sg];
      float y1 = (vv[sg].y - mean) * rstd * ga[2 * sg + 1] + be[2 * sg + 1];
      u32 p = (u32)f2bf(y0) | ((u32)f2bf(y1) << 16);
      int s16 = sg * 16 + (lane >> 2);
      *(u32*)&xh[(lr * 48 + (s16 ^ (lr & 7))) * 8 + (lane & 3) * 2] = p;
    }
  }
  // x visible to all waves; do NOT drain vmcnt (slab prefetch in flight)
  WAITLGKM0();
  __builtin_amdgcn_s_barrier();

  // ---- gemm1: all 64 rows x own 48 cols, K=384 (12 slabs) ----
  f32x4 acc1[4][3];
#pragma unroll
  for (int nt = 0; nt < 3; ++nt) {
    float bv = b1[wid * 48 + nt * 16 + l15];
#pragma unroll
    for (int m = 0; m < 4; ++m) acc1[m][nt] = (f32x4){bv, bv, bv, bv};
  }
  const int axr = l15 & 7;
  int aoff[4];
#pragma unroll
  for (int m = 0; m < 4; ++m) aoff[m] = (m * 16 + l15) * 384;
  int boff1[3];
#pragma unroll
  for (int nt = 0; nt < 3; ++nt) {
    int n = wid * 48 + nt * 16 + l15;
    boff1[nt] = (nt * 16 + l15) * 32 + (gq ^ ((n >> 1) & 3)) * 8;
  }

#pragma unroll
  for (int ks = 0; ks < 12; ++ks) {
    if (ks + 2 < 12) { STAGE1(ks + 2, (ks + 2) % 3); }
    if (ks + 2 < 12)      { WAITVM(6); }
    else if (ks + 1 < 12) { WAITVM(3); }
    else                  { WAITVM(0); }
    const u16* bsl = &bs[wid][ks % 3][0];
    const int asl = ((ks * 4 + gq) ^ axr) * 8;
    bf16x8 a[4], bb[3];
#pragma unroll
    for (int m = 0; m < 4; ++m) a[m] = *(const bf16x8*)&xh[aoff[m] + asl];
#pragma unroll
    for (int nt = 0; nt < 3; ++nt) bb[nt] = *(const bf16x8*)&bsl[boff1[nt]];
#pragma unroll
    for (int m = 0; m < 4; ++m)
#pragma unroll
      for (int nt = 0; nt < 3; ++nt)
        acc1[m][nt] = __builtin_amdgcn_mfma_f32_16x16x32_bf16(a[m], bb[nt], acc1[m][nt], 0, 0, 0);
  }
  __builtin_amdgcn_s_barrier();   // all x-reads complete before h overwrites xh

  // ---- gemm2 slab prefetch + gelu -> h into xh (same swizzle) ----
  float b2v = b2[wid * 16 + l15];
  const u16* w2base = w2s + (size_t)(wid * 16) * 32 + (size_t)lane * 8;
#define STAGE2(ks, buf) gload16(w2base + (size_t)(ks) * 4096, &bs[wid][buf][0])
  STAGE2(0, 0);
  STAGE2(1, 1);
#pragma unroll
  for (int m = 0; m < 4; ++m)
#pragma unroll
    for (int nt = 0; nt < 3; ++nt)
#pragma unroll
      for (int j = 0; j < 4; ++j) {
        int r = m * 16 + gq * 4 + j;
        int col = wid * 48 + nt * 16 + l15;
        xh[r * 384 + ((col >> 3) ^ (r & 7)) * 8 + (col & 7)] = f2bf(gelu_f(acc1[m][nt][j]));
      }
  WAITLGKM0();
  __builtin_amdgcn_s_barrier();

  // ---- gemm2: all 64 rows x own 16 cols, K=384 ----
  f32x4 acc2[4];
#pragma unroll
  for (int m = 0; m < 4; ++m) acc2[m] = (f32x4){b2v, b2v, b2v, b2v};
  const int boff2 = l15 * 32 + (gq ^ (((wid * 16 + l15) >> 1) & 3)) * 8;

#pragma unroll
  for (int ks = 0; ks < 12; ++ks) {
    if (ks + 2 < 12) { STAGE2(ks + 2, (ks + 2) % 3); }
    if (ks + 2 < 12)      { WAITVM(2); }
    else if (ks + 1 < 12) { WAITVM(1); }
    else                  { WAITVM(0); }
    const u16* bsl = &bs[wid][ks % 3][0];
    const int asl = ((ks * 4 + gq) ^ axr) * 8;
    bf16x8 bb = *(const bf16x8*)&bsl[boff2];
#pragma unroll
    for (int m = 0; m < 4; ++m) {
      bf16x8 a = *(const bf16x8*)&xh[aoff[m] + asl];
      acc2[m] = __builtin_amdgcn_mfma_f32_16x16x32_bf16(a, bb, acc2[m], 0, 0, 0);
    }
  }

  // ---- epilogue: own 16 cols ----
  const int col = wid * 16 + l15;
#pragma unroll
  for (int m = 0; m < 4; ++m)
#pragma unroll
    for (int j = 0; j < 4; ++j) {
      int r = row0 + m * 16 + gq * 4 + j;
      if (r < N_EDGE) {
        __half hv = __float2half(acc2[m][j]);
        if (store_eh) e_h[(size_t)r * 128 + col] = hv;
        out_edge[(size_t)r * 128 + col] = edge[(size_t)r * 128 + col] + __half2float(hv);
      }
    }
#undef STAGE1
#undef STAGE2
}

// ==================== fused node MLP =========================================
// 32 rows/block, 256 threads (4 waves). gemm1 wave owns 64 cols, gemm2 32.
// LDS: xh 16KB + bs 48KB = 64KB -> 2 blocks/CU.
__global__ __launch_bounds__(256, 2) void node_fused_kernel(
    const float* __restrict__ node, const __half* __restrict__ agg,
    const float* __restrict__ lng, const float* __restrict__ lnb,
    const u16* __restrict__ w1s, const float* __restrict__ b1,
    const u16* __restrict__ w2s, const float* __restrict__ b2,
    float* __restrict__ out_node) {
  const int lane = threadIdx.x & 63, wid = threadIdx.x >> 6;   // 0..3
  const int l15 = lane & 15, gq = lane >> 4;
  const int row0 = blockIdx.x * 32;

  __shared__ __align__(16) u16 xh[32 * 32 * 8];    // 16 KB, row pitch 256 u16
  __shared__ __align__(16) u16 bs[4][3][2048];     // 48 KB

  const u16* w1base = w1s + (size_t)(wid * 64) * 32 + (size_t)lane * 8;
#define NSTAGE1(ks, buf)                                        \
  { const u16* s_ = w1base + (size_t)(ks) * 8192;               \
    u16* d_ = &bs[wid][buf][0];                                 \
    gload16(s_, d_); gload16(s_ + 512, d_ + 512);               \
    gload16(s_ + 1024, d_ + 1024); gload16(s_ + 1536, d_ + 1536); }
  NSTAGE1(0, 0);
  NSTAGE1(1, 1);

  float ga[4], be[4];
#pragma unroll
  for (int s = 0; s < 2; ++s) {
    float2 g2 = *(const float2*)&lng[s * 128 + 2 * lane];
    float2 b2v = *(const float2*)&lnb[s * 128 + 2 * lane];
    ga[2 * s] = g2.x; ga[2 * s + 1] = g2.y;
    be[2 * s] = b2v.x; be[2 * s + 1] = b2v.y;
  }
  float2 v0[8], v1[8];
#pragma unroll
  for (int t = 0; t < 8; ++t) {
    int g = row0 + wid * 8 + t; if (g > N_NODE - 1) g = N_NODE - 1;
    v0[t] = *(const float2*)&node[(size_t)g * 128 + 2 * lane];
    v1[t] = __half22float2(*(const __half2*)&agg[(size_t)g * 128 + 2 * lane]);
  }
#pragma unroll
  for (int t = 0; t < 8; ++t) {
    float s  = v0[t].x + v0[t].y + v1[t].x + v1[t].y;
    float ss = v0[t].x*v0[t].x + v0[t].y*v0[t].y + v1[t].x*v1[t].x + v1[t].y*v1[t].y;
#pragma unroll
    for (int m = 1; m < 64; m <<= 1) { s += __shfl_xor(s, m); ss += __shfl_xor(ss, m); }
    float mean = s * (1.0f / 256.0f);
    float var  = ss * (1.0f / 256.0f) - mean * mean;
    float rstd = rsqrtf(var + 1e-5f);
    int lr = wid * 8 + t;
    float2 vv[2] = {v0[t], v1[t]};
#pragma unroll
    for (int sg = 0; sg < 2; ++sg) {
      float y0 = (vv[sg].x - mean) * rstd * ga[2 * sg]     + be[2 * sg];
      float y1 = (vv[sg].y - mean) * rstd * ga[2 * sg + 1] + be[2 * sg + 1];
      u32 p = (u32)f2bf(y0) | ((u32)f2bf(y1) << 16);
      int s16 = sg * 16 + (lane >> 2);
      *(u32*)&xh[(lr * 32 + (s16 ^ (lr & 7))) * 8 + (lane & 3) * 2] = p;
    }
  }
  WAITLGKM0();
  __builtin_amdgcn_s_barrier();

  // ---- gemm1: 32 rows x own 64 cols, K=256 (8 slabs) ----
  f32x4 acc1[2][4];
#pragma unroll
  for (int nt = 0; nt < 4; ++nt) {
    float bv = b1[wid * 64 + nt * 16 + l15];
#pragma unroll
    for (int m = 0; m < 2; ++m) acc1[m][nt] = (f32x4){bv, bv, bv, bv};
  }
  const int axr = l15 & 7;
  int aoff[2];
#pragma unroll
  for (int m = 0; m < 2; ++m) aoff[m] = (m * 16 + l15) * 256;
  int boff1[4];
#pragma unroll
  for (int nt = 0; nt < 4; ++nt) {
    int n = wid * 64 + nt * 16 + l15;
    boff1[nt] = (nt * 16 + l15) * 32 + (gq ^ ((n >> 1) & 3)) * 8;
  }

#pragma unroll
  for (int ks = 0; ks < 8; ++ks) {
    if (ks + 2 < 8) { NSTAGE1(ks + 2, (ks + 2) % 3); }
    if (ks + 2 < 8)      { WAITVM(8); }
    else if (ks + 1 < 8) { WAITVM(4); }
    else                 { WAITVM(0); }
    const u16* bsl = &bs[wid][ks % 3][0];
    const int asl = ((ks * 4 + gq) ^ axr) * 8;
    bf16x8 a[2], bb[4];
#pragma unroll
    for (int m = 0; m < 2; ++m) a[m] = *(const bf16x8*)&xh[aoff[m] + asl];
#pragma unroll
    for (int nt = 0; nt < 4; ++nt) bb[nt] = *(const bf16x8*)&bsl[boff1[nt]];
#pragma unroll
    for (int m = 0; m < 2; ++m)
#pragma unroll
      for (int nt = 0; nt < 4; ++nt)
        acc1[m][nt] = __builtin_amdgcn_mfma_f32_16x16x32_bf16(a[m], bb[nt], acc1[m][nt], 0, 0, 0);
  }
  __builtin_amdgcn_s_barrier();

  // ---- gemm2 prefetch + gelu -> h ----
  float b2a = b2[wid * 32 + l15];
  float b2b = b2[wid * 32 + 16 + l15];
  const u16* w2base = w2s + (size_t)(wid * 32) * 32 + (size_t)lane * 8;
#define NSTAGE2(ks, buf)                                        \
  { const u16* s_ = w2base + (size_t)(ks) * 4096;               \
    u16* d_ = &bs[wid][buf][0];                                 \
    gload16(s_, d_); gload16(s_ + 512, d_ + 512); }
  NSTAGE2(0, 0);
  NSTAGE2(1, 1);
#pragma unroll
  for (int m = 0; m < 2; ++m)
#pragma unroll
    for (int nt = 0; nt < 4; ++nt)
#pragma unroll
      for (int j = 0; j < 4; ++j) {
        int r = m * 16 + gq * 4 + j;
        int col = wid * 64 + nt * 16 + l15;
        xh[r * 256 + ((col >> 3) ^ (r & 7)) * 8 + (col & 7)] = f2bf(gelu_f(acc1[m][nt][j]));
      }
  WAITLGKM0();
  __builtin_amdgcn_s_barrier();

  // ---- gemm2: 32 rows x own 32 cols, K=256 ----
  f32x4 acc2[2][2];
#pragma unroll
  for (int m = 0; m < 2; ++m) {
    acc2[m][0] = (f32x4){b2a, b2a, b2a, b2a};
    acc2[m][1] = (f32x4){b2b, b2b, b2b, b2b};
  }
  int boff2[2];
#pragma unroll
  for (int nt = 0; nt < 2; ++nt) {
    int n = wid * 32 + nt * 16 + l15;
    boff2[nt] = (nt * 16 + l15) * 32 + (gq ^ ((n >> 1) & 3)) * 8;
  }

#pragma unroll
  for (int ks = 0; ks < 8; ++ks) {
    if (ks + 2 < 8) { NSTAGE2(ks + 2, (ks + 2) % 3); }
    if (ks + 2 < 8)      { WAITVM(4); }
    else if (ks + 1 < 8) { WAITVM(2); }
    else                 { WAITVM(0); }
    const u16* bsl = &bs[wid][ks % 3][0];
    const int asl = ((ks * 4 + gq) ^ axr) * 8;
    bf16x8 a[2], bb[2];
#pragma unroll
    for (int m = 0; m < 2; ++m) a[m] = *(const bf16x8*)&xh[aoff[m] + asl];
#pragma unroll
    for (int nt = 0; nt < 2; ++nt) bb[nt] = *(const bf16x8*)&bsl[boff2[nt]];
#pragma unroll
    for (int m = 0; m < 2; ++m)
#pragma unroll
      for (int nt = 0; nt < 2; ++nt)
        acc2[m][nt] = __builtin_amdgcn_mfma_f32_16x16x32_bf16(a[m], bb[nt], acc2[m][nt], 0, 0, 0);
  }

#pragma unroll
  for (int m = 0; m < 2; ++m)
#pragma unroll
    for (int nt = 0; nt < 2; ++nt)
#pragma unroll
      for (int j = 0; j < 4; ++j) {
        int r = row0 + m * 16 + gq * 4 + j;
        if (r < N_NODE) {
          int col = wid * 32 + nt * 16 + l15;
          out_node[(size_t)r * 128 + col] = node[(size_t)r * 128 + col] + acc2[m][nt][j];
        }
      }
#undef NSTAGE1
#undef NSTAGE2
}

// ---------------- scatter: agg[row] += fp16(e[col] * val), pk fp16 atomics ----
__global__ __launch_bounds__(256) void scatter_kernel(
    const int* __restrict__ rows, const int* __restrict__ cols,
    const float* __restrict__ vals,
    const __half* __restrict__ e_h,
    const float* __restrict__ out_edge, const float* __restrict__ edge,
    __half* __restrict__ agg, int use_eh) {
  long t = (long)blockIdx.x * 256 + threadIdx.x;
  int k = (int)(t >> 6);
  int l = (int)(t & 63);
  int r = rows[k], c = cols[k];
  float v = vals[k];
  __half2 h2;
  if (use_eh) {
    h2 = *(const __half2*)&e_h[(size_t)c * 128 + 2 * l];
  } else {
    size_t o = (size_t)c * 128 + 2 * l;
    float2 eo = *(const float2*)&out_edge[o];
    float2 e0 = *(const float2*)&edge[o];
    h2 = __floats2half2_rn(eo.x - e0.x, eo.y - e0.y);
  }
  h2 = __hmul2(h2, __float2half2_rn(v));
  unsafeAtomicAdd((__half2*)&agg[(size_t)r * 128 + 2 * l], h2);
}

extern "C" void kernel_launch(void* const* d_in, const int* in_sizes, int n_in,
                              void* d_out, int out_size, void* d_ws, size_t ws_size,
                              hipStream_t stream) {
  (void)in_sizes; (void)n_in; (void)out_size;
  const float* node    = (const float*)d_in[0];
  const float* edge    = (const float*)d_in[1];
  const int*   edgeIdx = (const int*)d_in[2];
  const int*   e2n_r   = (const int*)d_in[3];
  const int*   e2n_c   = (const int*)d_in[4];
  const float* e2n_v   = (const float*)d_in[5];
  const float* n1g     = (const float*)d_in[6];
  const float* n1b     = (const float*)d_in[7];
  const float* n2g     = (const float*)d_in[8];
  const float* n2b     = (const float*)d_in[9];
  const float* ew1     = (const float*)d_in[10];
  const float* eb1     = (const float*)d_in[11];
  const float* ew2     = (const float*)d_in[12];
  const float* eb2     = (const float*)d_in[13];
  const float* nw1     = (const float*)d_in[14];
  const float* nb1     = (const float*)d_in[15];
  const float* nw2     = (const float*)d_in[16];
  const float* nb2     = (const float*)d_in[17];

  float* out_node = (float*)d_out;
  float* out_edge = out_node + (size_t)N_NODE * 128;

  char* w = (char*)d_ws;
  auto alloc = [&](size_t bytes) { char* p = w; w += (bytes + 255) & ~(size_t)255; return p; };
  u16* ew1s = (u16*)alloc((size_t)384 * 384 * 2);
  u16* ew2s = (u16*)alloc((size_t)384 * 128 * 2);
  u16* nw1s = (u16*)alloc((size_t)256 * 256 * 2);
  u16* nw2s = (u16*)alloc((size_t)256 * 128 * 2);
  __half* agg = (__half*)alloc((size_t)N_NODE * 128 * 2);

  size_t used = (size_t)(w - (char*)d_ws);
  const size_t EH_BYTES = (size_t)N_EDGE * 128 * 2;   // 64 MB
  int use_eh = (ws_size >= used + EH_BYTES) ? 1 : 0;
  __half* e_h = nullptr;
  if (use_eh) e_h = (__half*)alloc(EH_BYTES);

  wprep_kernel<<<(384 * 384 + 255) / 256, 256, 0, stream>>>(ew1, ew1s, 384, 384);
  wprep_kernel<<<(384 * 128 + 255) / 256, 256, 0, stream>>>(ew2, ew2s, 384, 128);
  wprep_kernel<<<(256 * 256 + 255) / 256, 256, 0, stream>>>(nw1, nw1s, 256, 256);
  wprep_kernel<<<(256 * 128 + 255) / 256, 256, 0, stream>>>(nw2, nw2s, 256, 128);
  hipMemsetAsync(agg, 0, (size_t)N_NODE * 128 * 2, stream);

  edge_fused_kernel<<<(N_EDGE + 63) / 64, 512, 0, stream>>>(
      node, edge, edgeIdx, n1g, n1b, ew1s, eb1, ew2s, eb2, e_h, out_edge, use_eh);

  scatter_kernel<<<(NNZV * 64) / 256, 256, 0, stream>>>(
      e2n_r, e2n_c, e2n_v, e_h, out_edge, edge, agg, use_eh);

  node_fused_kernel<<<(N_NODE + 31) / 32, 256, 0, stream>>>(
      node, agg, n2g, n2b, nw1s, nb1, nw2s, nb2, out_node);
}

// Round 7
// 416.556 us; speedup vs baseline: 2.8155x; 1.1902x over previous
//
#include <hip/hip_runtime.h>
#include <hip/hip_fp16.h>

typedef unsigned short u16;
typedef unsigned int u32;

#define N_NODE 50000
#define N_EDGE 250000
#define NNZV   500000

typedef __attribute__((ext_vector_type(8))) __bf16 bf16x8;
typedef __attribute__((ext_vector_type(4))) float f32x4;

#define WAITVM(n) asm volatile("s_waitcnt vmcnt(" #n ")" ::: "memory")
#define WAITLGKM0() asm volatile("s_waitcnt lgkmcnt(0)" ::: "memory")
#define SBAR() __builtin_amdgcn_s_barrier()
#define SCHEDB() __builtin_amdgcn_sched_barrier(0)

static __device__ __forceinline__ u16 f2bf(float f) {
  union { float f; u32 u; } cv; cv.f = f;
  u32 u = cv.u;
  return (u16)((u + 0x7FFFu + ((u >> 16) & 1u)) >> 16);
}

// exact-erf gelu via A&S 7.1.26 poly (|erf err| <= 1.5e-7)
static __device__ __forceinline__ float gelu_f(float x) {
  float z = fabsf(x) * 0.70710678118654752f;
  float t = __builtin_amdgcn_rcpf(1.0f + 0.3275911f * z);
  float p = t * (0.254829592f + t * (-0.284496736f + t * (1.421413741f +
            t * (-1.453152027f + t * 1.061405429f))));
  float er = 1.0f - p * __expf(-z * z);
  er = copysignf(er, x);
  return 0.5f * x * (1.0f + er);
}

static __device__ __forceinline__ void gload16(const u16* g, u16* l) {
  __builtin_amdgcn_global_load_lds(
      (const __attribute__((address_space(1))) void*)g,
      (__attribute__((address_space(3))) void*)l,
      16, 0, 0);
}

// weights [in=K][out=N] f32 -> slab layout [K/32][N][4 chunks of 8, XOR-swizzled]
// phys chunk p holds logical chunk g = p ^ ((n>>1)&3)
__global__ void wprep_kernel(const float* __restrict__ in, u16* __restrict__ out,
                             int K, int N) {
  int idx = blockIdx.x * 256 + threadIdx.x;
  if (idx < K * N) {
    int k = idx / N, n = idx % N;
    int ks = k >> 5, g = (k >> 3) & 3, e = k & 7;
    int p = g ^ ((n >> 1) & 3);
    out[((size_t)ks * N + n) * 32 + p * 8 + e] = f2bf(in[(size_t)k * N + n]);
  }
}

// ==================== fused edge MLP =========================================
// 64 rows, 512 thr (8 waves x 48 cols gemm1 / 16 cols gemm2).
// x/h streamed through a 16KB 128-col part buffer (slot-XOR swizzled);
// wave-private ring-2 slabs. Ring-2 overwrite is fenced: WAITLGKM0 before each
// stage guarantees this wave's ds_reads of that buffer executed first;
// sched_barrier(0) pins compile-time order at waits/barriers.
// LDS 64KB -> 2 blocks/CU -> 4 waves/SIMD.
__global__ __launch_bounds__(512, 4) void edge_fused_kernel(
    const float* __restrict__ node, const float* __restrict__ edge,
    const int* __restrict__ edgeIdx,
    const float* __restrict__ lng, const float* __restrict__ lnb,
    const u16* __restrict__ w1s, const float* __restrict__ b1,
    const u16* __restrict__ w2s, const float* __restrict__ b2,
    __half* __restrict__ e_h, float* __restrict__ out_edge, int store_eh) {
  const int lane = threadIdx.x & 63, wid = threadIdx.x >> 6;   // 0..7
  const int l15 = lane & 15, gq = lane >> 4;
  const int row0 = blockIdx.x * 64;

  __shared__ __align__(16) u16 xp[64 * 128];      // 16 KB part buffer (x, then h)
  __shared__ __align__(16) u16 ring[8][2][1536];  // 48 KB wave-private rings

  // ---- W1 ring prologue (slabs 0,1) ----
  const u16* w1base = w1s + (size_t)(wid * 48) * 32 + (size_t)lane * 8;
#define ESTG1(s, b) { const u16* s_ = w1base + (size_t)(s) * 12288;          \
    u16* d_ = &ring[wid][b][0];                                              \
    gload16(s_, d_); gload16(s_ + 512, d_ + 512); gload16(s_ + 1024, d_ + 1024); }
  ESTG1(0, 0); ESTG1(1, 1);

  // ---- LN + gather: 8 rows/wave, LN output packed to 24 VGPRs ----
  float ga[6], be[6];
#pragma unroll
  for (int s = 0; s < 3; ++s) {
    float2 g2 = *(const float2*)&lng[s * 128 + 2 * lane];
    float2 b2v = *(const float2*)&lnb[s * 128 + 2 * lane];
    ga[2 * s] = g2.x; ga[2 * s + 1] = g2.y;
    be[2 * s] = b2v.x; be[2 * s + 1] = b2v.y;
  }
  u32 xq[8][3];
  {
    int gi[8], ia[8], ib[8];
#pragma unroll
    for (int t = 0; t < 8; ++t) {
      int g = row0 + wid * 8 + t; if (g > N_EDGE - 1) g = N_EDGE - 1;
      gi[t] = g;
      int2 ab = *(const int2*)&edgeIdx[2 * g];
      ia[t] = ab.x; ib[t] = ab.y;
    }
    float2 v0[8], v1[8], v2[8];
#pragma unroll
    for (int t = 0; t < 8; ++t) {
      v0[t] = *(const float2*)&edge[(size_t)gi[t] * 128 + 2 * lane];
      v1[t] = *(const float2*)&node[(size_t)ia[t] * 128 + 2 * lane];
      v2[t] = *(const float2*)&node[(size_t)ib[t] * 128 + 2 * lane];
    }
#pragma unroll
    for (int t = 0; t < 8; ++t) {
      float s  = v0[t].x + v0[t].y + v1[t].x + v1[t].y + v2[t].x + v2[t].y;
      float ss = v0[t].x*v0[t].x + v0[t].y*v0[t].y + v1[t].x*v1[t].x +
                 v1[t].y*v1[t].y + v2[t].x*v2[t].x + v2[t].y*v2[t].y;
#pragma unroll
      for (int m = 1; m < 64; m <<= 1) { s += __shfl_xor(s, m); ss += __shfl_xor(ss, m); }
      float mean = s * (1.0f / 384.0f);
      float var  = ss * (1.0f / 384.0f) - mean * mean;
      float rstd = rsqrtf(var + 1e-5f);
      float2 vv[3] = {v0[t], v1[t], v2[t]};
#pragma unroll
      for (int sg = 0; sg < 3; ++sg) {
        float y0 = (vv[sg].x - mean) * rstd * ga[2 * sg]     + be[2 * sg];
        float y1 = (vv[sg].y - mean) * rstd * ga[2 * sg + 1] + be[2 * sg + 1];
        xq[t][sg] = (u32)f2bf(y0) | ((u32)f2bf(y1) << 16);
      }
    }
  }

  // ---- gemm1: 12 slabs in 3 parts; wave owns cols [48*wid, +48) ----
  f32x4 acc1[4][3];
#pragma unroll
  for (int nt = 0; nt < 3; ++nt) {
    float bv = b1[wid * 48 + nt * 16 + l15];
#pragma unroll
    for (int m = 0; m < 4; ++m) acc1[m][nt] = (f32x4){bv, bv, bv, bv};
  }
  int aoff[4];
#pragma unroll
  for (int m = 0; m < 4; ++m) aoff[m] = (m * 16 + l15) * 128;
  const int bperm = (gq ^ ((l15 >> 1) & 3)) * 8;
  int boff[3];
#pragma unroll
  for (int nt = 0; nt < 3; ++nt) boff[nt] = (nt * 16 + l15) * 32 + bperm;

#pragma unroll
  for (int p = 0; p < 3; ++p) {
#pragma unroll
    for (int t = 0; t < 8; ++t) {
      int lr = wid * 8 + t;
      *(u32*)&xp[lr * 128 + ((lane >> 2) ^ (lr & 15)) * 8 + (lane & 3) * 2] = xq[t][p];
    }
    WAITLGKM0(); SCHEDB(); SBAR(); SCHEDB();
#pragma unroll
    for (int sp = 0; sp < 4; ++sp) {
      const int s = 4 * p + sp;
      if (s < 11) { WAITVM(3); } else { WAITVM(0); }
      SCHEDB();
      const u16* bsl = &ring[wid][s & 1][0];
      const int axi = ((sp * 4 + gq) ^ l15) * 8;
      bf16x8 a[4], bb[3];
#pragma unroll
      for (int m = 0; m < 4; ++m) a[m] = *(const bf16x8*)&xp[aoff[m] + axi];
#pragma unroll
      for (int nt = 0; nt < 3; ++nt) bb[nt] = *(const bf16x8*)&bsl[boff[nt]];
#pragma unroll
      for (int m = 0; m < 4; ++m)
#pragma unroll
        for (int nt = 0; nt < 3; ++nt)
          acc1[m][nt] = __builtin_amdgcn_mfma_f32_16x16x32_bf16(a[m], bb[nt], acc1[m][nt], 0, 0, 0);
      if (s + 2 < 12) { WAITLGKM0(); SCHEDB(); ESTG1(s + 2, s & 1); }
    }
    SCHEDB(); SBAR(); SCHEDB();   // all reads of part p done before overwrite
  }

  // ---- W2 ring prologue + gelu -> packed h ----
  const u16* w2base = w2s + (size_t)(wid * 16) * 32 + (size_t)lane * 8;
#define ESTG2(s, b) gload16(w2base + (size_t)(s) * 4096, &ring[wid][b][0])
  ESTG2(0, 0); ESTG2(1, 1);
  u32 hq[4][3][2];
#pragma unroll
  for (int m = 0; m < 4; ++m)
#pragma unroll
    for (int nt = 0; nt < 3; ++nt) {
      float g0 = gelu_f(acc1[m][nt][0]), g1 = gelu_f(acc1[m][nt][1]);
      float g2 = gelu_f(acc1[m][nt][2]), g3 = gelu_f(acc1[m][nt][3]);
      hq[m][nt][0] = (u32)f2bf(g0) | ((u32)f2bf(g1) << 16);
      hq[m][nt][1] = (u32)f2bf(g2) | ((u32)f2bf(g3) << 16);
    }

  // ---- gemm2: 12 slabs in 3 parts; wave owns cols [16*wid, +16) ----
  float b2v = b2[wid * 16 + l15];
  f32x4 acc2[4];
#pragma unroll
  for (int m = 0; m < 4; ++m) acc2[m] = (f32x4){b2v, b2v, b2v, b2v};
  const int bo2 = l15 * 32 + bperm;

#pragma unroll
  for (int p = 0; p < 3; ++p) {
#pragma unroll
    for (int m = 0; m < 4; ++m)
#pragma unroll
      for (int nt = 0; nt < 3; ++nt) {
        const int col0 = 48 * wid + 16 * nt;
        if ((col0 >> 7) == p) {
          const int cp = (col0 & 127) + l15;
          const int sl = cp >> 3, ip = cp & 7;
#pragma unroll
          for (int j = 0; j < 4; ++j) {
            int r = m * 16 + gq * 4 + j;
            xp[r * 128 + (sl ^ (r & 15)) * 8 + ip] =
                (u16)(hq[m][nt][j >> 1] >> ((j & 1) * 16));
          }
        }
      }
    WAITLGKM0(); SCHEDB(); SBAR(); SCHEDB();
#pragma unroll
    for (int sp = 0; sp < 4; ++sp) {
      const int g = 4 * p + sp;
      if (g < 11) { WAITVM(1); } else { WAITVM(0); }
      SCHEDB();
      const int axi = ((sp * 4 + gq) ^ l15) * 8;
      bf16x8 a[4];
#pragma unroll
      for (int m = 0; m < 4; ++m) a[m] = *(const bf16x8*)&xp[aoff[m] + axi];
      bf16x8 bb = *(const bf16x8*)&ring[wid][g & 1][bo2];
#pragma unroll
      for (int m = 0; m < 4; ++m)
        acc2[m] = __builtin_amdgcn_mfma_f32_16x16x32_bf16(a[m], bb, acc2[m], 0, 0, 0);
      if (g + 2 < 12) { WAITLGKM0(); SCHEDB(); ESTG2(g + 2, g & 1); }
    }
    if (p < 2) { SCHEDB(); SBAR(); SCHEDB(); }
  }

  // ---- epilogue ----
  const int col = wid * 16 + l15;
#pragma unroll
  for (int m = 0; m < 4; ++m)
#pragma unroll
    for (int j = 0; j < 4; ++j) {
      int r = row0 + m * 16 + gq * 4 + j;
      if (r < N_EDGE) {
        __half hv = __float2half(acc2[m][j]);
        if (store_eh) e_h[(size_t)r * 128 + col] = hv;
        out_edge[(size_t)r * 128 + col] = edge[(size_t)r * 128 + col] + __half2float(hv);
      }
    }
#undef ESTG1
#undef ESTG2
}

// ==================== fused node MLP =========================================
// Same structure: K=256 (8 slabs, 2 parts), gemm1 32 cols/wave, gemm2 16.
// LDS 48KB.
__global__ __launch_bounds__(512, 4) void node_fused_kernel(
    const float* __restrict__ node, const __half* __restrict__ agg,
    const float* __restrict__ lng, const float* __restrict__ lnb,
    const u16* __restrict__ w1s, const float* __restrict__ b1,
    const u16* __restrict__ w2s, const float* __restrict__ b2,
    float* __restrict__ out_node) {
  const int lane = threadIdx.x & 63, wid = threadIdx.x >> 6;
  const int l15 = lane & 15, gq = lane >> 4;
  const int row0 = blockIdx.x * 64;

  __shared__ __align__(16) u16 xp[64 * 128];      // 16 KB
  __shared__ __align__(16) u16 ring[8][2][1024];  // 32 KB

  const u16* w1base = w1s + (size_t)(wid * 32) * 32 + (size_t)lane * 8;
#define NSTG1(s, b) { const u16* s_ = w1base + (size_t)(s) * 8192;           \
    u16* d_ = &ring[wid][b][0];                                              \
    gload16(s_, d_); gload16(s_ + 512, d_ + 512); }
  NSTG1(0, 0); NSTG1(1, 1);

  float ga[4], be[4];
#pragma unroll
  for (int s = 0; s < 2; ++s) {
    float2 g2 = *(const float2*)&lng[s * 128 + 2 * lane];
    float2 b2v = *(const float2*)&lnb[s * 128 + 2 * lane];
    ga[2 * s] = g2.x; ga[2 * s + 1] = g2.y;
    be[2 * s] = b2v.x; be[2 * s + 1] = b2v.y;
  }
  u32 xq[8][2];
  {
    float2 v0[8], v1[8];
#pragma unroll
    for (int t = 0; t < 8; ++t) {
      int g = row0 + wid * 8 + t; if (g > N_NODE - 1) g = N_NODE - 1;
      v0[t] = *(const float2*)&node[(size_t)g * 128 + 2 * lane];
      v1[t] = __half22float2(*(const __half2*)&agg[(size_t)g * 128 + 2 * lane]);
    }
#pragma unroll
    for (int t = 0; t < 8; ++t) {
      float s  = v0[t].x + v0[t].y + v1[t].x + v1[t].y;
      float ss = v0[t].x*v0[t].x + v0[t].y*v0[t].y + v1[t].x*v1[t].x + v1[t].y*v1[t].y;
#pragma unroll
      for (int m = 1; m < 64; m <<= 1) { s += __shfl_xor(s, m); ss += __shfl_xor(ss, m); }
      float mean = s * (1.0f / 256.0f);
      float var  = ss * (1.0f / 256.0f) - mean * mean;
      float rstd = rsqrtf(var + 1e-5f);
      float2 vv[2] = {v0[t], v1[t]};
#pragma unroll
      for (int sg = 0; sg < 2; ++sg) {
        float y0 = (vv[sg].x - mean) * rstd * ga[2 * sg]     + be[2 * sg];
        float y1 = (vv[sg].y - mean) * rstd * ga[2 * sg + 1] + be[2 * sg + 1];
        xq[t][sg] = (u32)f2bf(y0) | ((u32)f2bf(y1) << 16);
      }
    }
  }

  f32x4 acc1[4][2];
#pragma unroll
  for (int nt = 0; nt < 2; ++nt) {
    float bv = b1[wid * 32 + nt * 16 + l15];
#pragma unroll
    for (int m = 0; m < 4; ++m) acc1[m][nt] = (f32x4){bv, bv, bv, bv};
  }
  int aoff[4];
#pragma unroll
  for (int m = 0; m < 4; ++m) aoff[m] = (m * 16 + l15) * 128;
  const int bperm = (gq ^ ((l15 >> 1) & 3)) * 8;
  int boff[2];
#pragma unroll
  for (int nt = 0; nt < 2; ++nt) boff[nt] = (nt * 16 + l15) * 32 + bperm;

#pragma unroll
  for (int p = 0; p < 2; ++p) {
#pragma unroll
    for (int t = 0; t < 8; ++t) {
      int lr = wid * 8 + t;
      *(u32*)&xp[lr * 128 + ((lane >> 2) ^ (lr & 15)) * 8 + (lane & 3) * 2] = xq[t][p];
    }
    WAITLGKM0(); SCHEDB(); SBAR(); SCHEDB();
#pragma unroll
    for (int sp = 0; sp < 4; ++sp) {
      const int s = 4 * p + sp;
      if (s < 7) { WAITVM(2); } else { WAITVM(0); }
      SCHEDB();
      const u16* bsl = &ring[wid][s & 1][0];
      const int axi = ((sp * 4 + gq) ^ l15) * 8;
      bf16x8 a[4], bb[2];
#pragma unroll
      for (int m = 0; m < 4; ++m) a[m] = *(const bf16x8*)&xp[aoff[m] + axi];
#pragma unroll
      for (int nt = 0; nt < 2; ++nt) bb[nt] = *(const bf16x8*)&bsl[boff[nt]];
#pragma unroll
      for (int m = 0; m < 4; ++m)
#pragma unroll
        for (int nt = 0; nt < 2; ++nt)
          acc1[m][nt] = __builtin_amdgcn_mfma_f32_16x16x32_bf16(a[m], bb[nt], acc1[m][nt], 0, 0, 0);
      if (s + 2 < 8) { WAITLGKM0(); SCHEDB(); NSTG1(s + 2, s & 1); }
    }
    SCHEDB(); SBAR(); SCHEDB();
  }

  const u16* w2base = w2s + (size_t)(wid * 16) * 32 + (size_t)lane * 8;
#define NSTG2(s, b) gload16(w2base + (size_t)(s) * 4096, &ring[wid][b][0])
  NSTG2(0, 0); NSTG2(1, 1);
  u32 hq[4][2][2];
#pragma unroll
  for (int m = 0; m < 4; ++m)
#pragma unroll
    for (int nt = 0; nt < 2; ++nt) {
      float g0 = gelu_f(acc1[m][nt][0]), g1 = gelu_f(acc1[m][nt][1]);
      float g2 = gelu_f(acc1[m][nt][2]), g3 = gelu_f(acc1[m][nt][3]);
      hq[m][nt][0] = (u32)f2bf(g0) | ((u32)f2bf(g1) << 16);
      hq[m][nt][1] = (u32)f2bf(g2) | ((u32)f2bf(g3) << 16);
    }

  float b2v = b2[wid * 16 + l15];
  f32x4 acc2[4];
#pragma unroll
  for (int m = 0; m < 4; ++m) acc2[m] = (f32x4){b2v, b2v, b2v, b2v};
  const int bo2 = l15 * 32 + bperm;

#pragma unroll
  for (int p = 0; p < 2; ++p) {
#pragma unroll
    for (int m = 0; m < 4; ++m)
#pragma unroll
      for (int nt = 0; nt < 2; ++nt) {
        const int col0 = 32 * wid + 16 * nt;
        if ((col0 >> 7) == p) {
          const int cp = (col0 & 127) + l15;
          const int sl = cp >> 3, ip = cp & 7;
#pragma unroll
          for (int j = 0; j < 4; ++j) {
            int r = m * 16 + gq * 4 + j;
            xp[r * 128 + (sl ^ (r & 15)) * 8 + ip] =
                (u16)(hq[m][nt][j >> 1] >> ((j & 1) * 16));
          }
        }
      }
    WAITLGKM0(); SCHEDB(); SBAR(); SCHEDB();
#pragma unroll
    for (int sp = 0; sp < 4; ++sp) {
      const int g = 4 * p + sp;
      if (g < 7) { WAITVM(1); } else { WAITVM(0); }
      SCHEDB();
      const int axi = ((sp * 4 + gq) ^ l15) * 8;
      bf16x8 a[4];
#pragma unroll
      for (int m = 0; m < 4; ++m) a[m] = *(const bf16x8*)&xp[aoff[m] + axi];
      bf16x8 bb = *(const bf16x8*)&ring[wid][g & 1][bo2];
#pragma unroll
      for (int m = 0; m < 4; ++m)
        acc2[m] = __builtin_amdgcn_mfma_f32_16x16x32_bf16(a[m], bb, acc2[m], 0, 0, 0);
      if (g + 2 < 8) { WAITLGKM0(); SCHEDB(); NSTG2(g + 2, g & 1); }
    }
    if (p < 1) { SCHEDB(); SBAR(); SCHEDB(); }
  }

  const int col = wid * 16 + l15;
#pragma unroll
  for (int m = 0; m < 4; ++m)
#pragma unroll
    for (int j = 0; j < 4; ++j) {
      int r = row0 + m * 16 + gq * 4 + j;
      if (r < N_NODE) {
        out_node[(size_t)r * 128 + col] = node[(size_t)r * 128 + col] + acc2[m][j];
      }
    }
#undef NSTG1
#undef NSTG2
}

// ---------------- scatter: agg[row] += fp16(e[col] * val), pk fp16 atomics ----
__global__ __launch_bounds__(256) void scatter_kernel(
    const int* __restrict__ rows, const int* __restrict__ cols,
    const float* __restrict__ vals,
    const __half* __restrict__ e_h,
    const float* __restrict__ out_edge, const float* __restrict__ edge,
    __half* __restrict__ agg, int use_eh) {
  long t = (long)blockIdx.x * 256 + threadIdx.x;
  int k = (int)(t >> 6);
  int l = (int)(t & 63);
  int r = rows[k], c = cols[k];
  float v = vals[k];
  __half2 h2;
  if (use_eh) {
    h2 = *(const __half2*)&e_h[(size_t)c * 128 + 2 * l];
  } else {
    size_t o = (size_t)c * 128 + 2 * l;
    float2 eo = *(const float2*)&out_edge[o];
    float2 e0 = *(const float2*)&edge[o];
    h2 = __floats2half2_rn(eo.x - e0.x, eo.y - e0.y);
  }
  h2 = __hmul2(h2, __float2half2_rn(v));
  unsafeAtomicAdd((__half2*)&agg[(size_t)r * 128 + 2 * l], h2);
}

extern "C" void kernel_launch(void* const* d_in, const int* in_sizes, int n_in,
                              void* d_out, int out_size, void* d_ws, size_t ws_size,
                              hipStream_t stream) {
  (void)in_sizes; (void)n_in; (void)out_size;
  const float* node    = (const float*)d_in[0];
  const float* edge    = (const float*)d_in[1];
  const int*   edgeIdx = (const int*)d_in[2];
  const int*   e2n_r   = (const int*)d_in[3];
  const int*   e2n_c   = (const int*)d_in[4];
  const float* e2n_v   = (const float*)d_in[5];
  const float* n1g     = (const float*)d_in[6];
  const float* n1b     = (const float*)d_in[7];
  const float* n2g     = (const float*)d_in[8];
  const float* n2b     = (const float*)d_in[9];
  const float* ew1     = (const float*)d_in[10];
  const float* eb1     = (const float*)d_in[11];
  const float* ew2     = (const float*)d_in[12];
  const float* eb2     = (const float*)d_in[13];
  const float* nw1     = (const float*)d_in[14];
  const float* nb1     = (const float*)d_in[15];
  const float* nw2     = (const float*)d_in[16];
  const float* nb2     = (const float*)d_in[17];

  float* out_node = (float*)d_out;
  float* out_edge = out_node + (size_t)N_NODE * 128;

  char* w = (char*)d_ws;
  auto alloc = [&](size_t bytes) { char* p = w; w += (bytes + 255) & ~(size_t)255; return p; };
  u16* ew1s = (u16*)alloc((size_t)384 * 384 * 2);
  u16* ew2s = (u16*)alloc((size_t)384 * 128 * 2);
  u16* nw1s = (u16*)alloc((size_t)256 * 256 * 2);
  u16* nw2s = (u16*)alloc((size_t)256 * 128 * 2);
  __half* agg = (__half*)alloc((size_t)N_NODE * 128 * 2);

  size_t used = (size_t)(w - (char*)d_ws);
  const size_t EH_BYTES = (size_t)N_EDGE * 128 * 2;   // 64 MB
  int use_eh = (ws_size >= used + EH_BYTES) ? 1 : 0;
  __half* e_h = nullptr;
  if (use_eh) e_h = (__half*)alloc(EH_BYTES);

  wprep_kernel<<<(384 * 384 + 255) / 256, 256, 0, stream>>>(ew1, ew1s, 384, 384);
  wprep_kernel<<<(384 * 128 + 255) / 256, 256, 0, stream>>>(ew2, ew2s, 384, 128);
  wprep_kernel<<<(256 * 256 + 255) / 256, 256, 0, stream>>>(nw1, nw1s, 256, 256);
  wprep_kernel<<<(256 * 128 + 255) / 256, 256, 0, stream>>>(nw2, nw2s, 256, 128);
  hipMemsetAsync(agg, 0, (size_t)N_NODE * 128 * 2, stream);

  edge_fused_kernel<<<(N_EDGE + 63) / 64, 512, 0, stream>>>(
      node, edge, edgeIdx, n1g, n1b, ew1s, eb1, ew2s, eb2, e_h, out_edge, use_eh);

  scatter_kernel<<<(NNZV * 64) / 256, 256, 0, stream>>>(
      e2n_r, e2n_c, e2n_v, e_h, out_edge, edge, agg, use_eh);

  node_fused_kernel<<<(N_NODE + 63) / 64, 512, 0, stream>>>(
      node, agg, n2g, n2b, nw1s, nb1, nw2s, nb2, out_node);
}